// Round 1
// baseline (505.225 us; speedup 1.0000x reference)
//
#include <hip/hip_runtime.h>

typedef _Float16 half8 __attribute__((ext_vector_type(8)));
typedef _Float16 half4v __attribute__((ext_vector_type(4)));
typedef float f32x4 __attribute__((ext_vector_type(4)));

// ---------------------------------------------------------------------------
// Convert Wq||Wk||Wv (fp32 [O,512] each) -> Wb fp16 [1024][512] (c-inner)
// ---------------------------------------------------------------------------
__global__ __launch_bounds__(256) void conv_w(const float* __restrict__ Wq,
                                              const float* __restrict__ Wk,
                                              const float* __restrict__ Wv,
                                              _Float16* __restrict__ Wb) {
  int idx = blockIdx.x * 256 + threadIdx.x;  // 0 .. 1024*512
  int row = idx >> 9;
  float v;
  if (row < 256)      v = Wq[idx];
  else if (row < 512) v = Wk[idx - 256 * 512];
  else                v = Wv[idx - 512 * 512];
  Wb[idx] = (_Float16)v;
}

// ---------------------------------------------------------------------------
// x fp32 [B][512][2048] -> xT fp16 [B][2048][512]   (LDS-tiled transpose)
// ---------------------------------------------------------------------------
__global__ __launch_bounds__(256) void conv_xT(const float* __restrict__ x,
                                               _Float16* __restrict__ xT) {
  __shared__ float T[32][33];
  const int b = blockIdx.z;
  const int n0 = blockIdx.x * 32, c0 = blockIdx.y * 32;
  const int tx = threadIdx.x & 31, ty = threadIdx.x >> 5;  // ty in 0..7
  const float* xb = x + (size_t)b * 512 * 2048;
#pragma unroll
  for (int r = 0; r < 4; r++)
    T[ty + r * 8][tx] = xb[(size_t)(c0 + ty + r * 8) * 2048 + n0 + tx];
  __syncthreads();
  _Float16* xtb = xT + (size_t)b * 2048 * 512;
#pragma unroll
  for (int r = 0; r < 4; r++)
    xtb[(size_t)(n0 + ty + r * 8) * 512 + c0 + tx] = (_Float16)T[tx][ty + r * 8];
}

// ---------------------------------------------------------------------------
// NT-GEMM: C[m][n] = sum_k A[m][k]*B[n][k].  A fp16 [M,K] lda, B fp16 [N,K] ldb.
// Block 256 thr = 4 waves; block tile 128x128; wave tile 64x64 (4x4 MFMAs).
// TR=false: C[m*ldc + n].  TR=true: C[n*ldc + m]  (transposed output).
// Grid: (N/128, M/128, batches). All of M,N mult of 128; K mult of 32.
// ---------------------------------------------------------------------------
template <typename OutT, bool TR>
__global__ __launch_bounds__(256) void gemm_nt(const _Float16* __restrict__ A,
                                               const _Float16* __restrict__ B,
                                               OutT* __restrict__ C, int K,
                                               int lda, int ldb, int ldc,
                                               long sA, long sB, long sC) {
  A += (size_t)blockIdx.z * sA;
  B += (size_t)blockIdx.z * sB;
  C += (size_t)blockIdx.z * sC;
  const int m_blk = blockIdx.y * 128, n_blk = blockIdx.x * 128;

  __shared__ _Float16 As[4096];  // [128 rows][32 k]  (k-inner, 16B frag reads)
  __shared__ _Float16 Bs[4096];

  const int t = threadIdx.x;
  const int lane = t & 63, wave = t >> 6;
  const int quad = lane >> 4, l16 = lane & 15;
  const int wm = (wave & 1) * 64, wn = (wave >> 1) * 64;

  // staging: chunk c covers row c/4, k-offset (c%4)*8; thread t does c=t, c=t+256
  const int r0 = t >> 2, ko = (t & 3) * 8;
  const _Float16* pa0 = A + (size_t)(m_blk + r0) * lda + ko;
  const _Float16* pa1 = A + (size_t)(m_blk + r0 + 64) * lda + ko;
  const _Float16* pb0 = B + (size_t)(n_blk + r0) * ldb + ko;
  const _Float16* pb1 = B + (size_t)(n_blk + r0 + 64) * ldb + ko;

  f32x4 acc[4][4] = {};

  for (int k0 = 0; k0 < K; k0 += 32) {
    uint4 a0 = *(const uint4*)(pa0 + k0);
    uint4 a1 = *(const uint4*)(pa1 + k0);
    uint4 b0 = *(const uint4*)(pb0 + k0);
    uint4 b1 = *(const uint4*)(pb1 + k0);
    __syncthreads();  // previous iter's readers done
    *(uint4*)&As[t * 8] = a0;
    *(uint4*)&As[2048 + t * 8] = a1;
    *(uint4*)&Bs[t * 8] = b0;
    *(uint4*)&Bs[2048 + t * 8] = b1;
    __syncthreads();
    half8 af[4], bf[4];
#pragma unroll
    for (int i = 0; i < 4; i++) {
      af[i] = *(const half8*)&As[(wm + i * 16 + l16) * 32 + quad * 8];
      bf[i] = *(const half8*)&Bs[(wn + i * 16 + l16) * 32 + quad * 8];
    }
#pragma unroll
    for (int i = 0; i < 4; i++)
#pragma unroll
      for (int j = 0; j < 4; j++)
        acc[i][j] =
            __builtin_amdgcn_mfma_f32_16x16x32_f16(af[i], bf[j], acc[i][j], 0, 0, 0);
  }

  // epilogue: D element (row = quad*4 + reg, col = l16) within each 16x16 tile
#pragma unroll
  for (int i = 0; i < 4; i++) {
    const int m0 = m_blk + wm + i * 16 + quad * 4;
#pragma unroll
    for (int j = 0; j < 4; j++) {
      const int n0 = n_blk + wn + j * 16 + l16;
      if constexpr (TR) {
        if constexpr (sizeof(OutT) == 4) {
          *(f32x4*)&C[(size_t)n0 * ldc + m0] = acc[i][j];
        } else {
          half4v h;
          h[0] = (_Float16)acc[i][j][0];
          h[1] = (_Float16)acc[i][j][1];
          h[2] = (_Float16)acc[i][j][2];
          h[3] = (_Float16)acc[i][j][3];
          *(half4v*)&C[(size_t)n0 * ldc + m0] = h;
        }
      } else {
#pragma unroll
        for (int r = 0; r < 4; r++)
          C[(size_t)(m0 + r) * ldc + n0] = (OutT)acc[i][j][r];
      }
    }
  }
}

// ---------------------------------------------------------------------------
// Column stats over simT [2048 rows (softmax axis)][2048 cols (k)]:
// cmax[k] = max_rows, cinv[k] = 1/sum_rows exp(. - cmax).
// Grid (2048/64, nb); block 256 = 4 waves x 64 cols.
// ---------------------------------------------------------------------------
__global__ __launch_bounds__(256) void colstats(const float* __restrict__ simT,
                                                float* __restrict__ cmax,
                                                float* __restrict__ cinv) {
  const int b = blockIdx.y;
  const float* S = simT + (size_t)b * 2048 * 2048;
  const int c = threadIdx.x & 63, w = threadIdx.x >> 6;
  const int col = blockIdx.x * 64 + c;
  __shared__ float red[4][64];

  float m = -3.0e38f;
  for (int r = w; r < 2048; r += 4) m = fmaxf(m, S[(size_t)r * 2048 + col]);
  red[w][c] = m;
  __syncthreads();
  m = fmaxf(fmaxf(red[0][c], red[1][c]), fmaxf(red[2][c], red[3][c]));
  __syncthreads();

  float s = 0.f;
  for (int r = w; r < 2048; r += 4) s += __expf(S[(size_t)r * 2048 + col] - m);
  red[w][c] = s;
  __syncthreads();
  if (w == 0) {
    s = red[0][c] + red[1][c] + red[2][c] + red[3][c];
    cmax[(size_t)b * 2048 + col] = m;
    cinv[(size_t)b * 2048 + col] = 1.0f / s;
  }
}

// ---------------------------------------------------------------------------
// attnT[m][k] = fp16( exp(simT[m][k]-cmax[k]) * cinv[k] ).  Grid (4096, nb).
// ---------------------------------------------------------------------------
__global__ __launch_bounds__(256) void attnscale(const float* __restrict__ simT,
                                                 const float* __restrict__ cmax,
                                                 const float* __restrict__ cinv,
                                                 _Float16* __restrict__ attnT) {
  const size_t b = blockIdx.y;
  const size_t g = (size_t)blockIdx.x * 256 + threadIdx.x;  // float4 group
  const int cg = (int)(g & 511);
  f32x4 s = *(const f32x4*)(simT + b * (2048ull * 2048) + g * 4);
  f32x4 mx = *(const f32x4*)(cmax + b * 2048 + cg * 4);
  f32x4 iv = *(const f32x4*)(cinv + b * 2048 + cg * 4);
  half4v h;
  h[0] = (_Float16)(__expf(s[0] - mx[0]) * iv[0]);
  h[1] = (_Float16)(__expf(s[1] - mx[1]) * iv[1]);
  h[2] = (_Float16)(__expf(s[2] - mx[2]) * iv[2]);
  h[3] = (_Float16)(__expf(s[3] - mx[3]) * iv[3]);
  *(half4v*)(attnT + b * (2048ull * 2048) + g * 4) = h;
}

// ---------------------------------------------------------------------------
extern "C" void kernel_launch(void* const* d_in, const int* in_sizes, int n_in,
                              void* d_out, int out_size, void* d_ws,
                              size_t ws_size, hipStream_t stream) {
  const float* x = (const float*)d_in[0];
  const float* Wq = (const float*)d_in[1];
  const float* Wk = (const float*)d_in[2];
  const float* Wv = (const float*)d_in[3];
  float* out = (float*)d_out;

  char* p = (char*)d_ws;
  auto alloc = [&](size_t bytes) -> char* {
    char* r = p;
    p += (bytes + 255) & ~(size_t)255;
    return r;
  };
  const size_t NB = 8, N = 2048, CIN = 512, CK = 256, CO = 512;
  _Float16* Wb = (_Float16*)alloc(1024 * 512 * sizeof(_Float16));
  _Float16* xT = (_Float16*)alloc(NB * N * CIN * sizeof(_Float16));
  _Float16* qkT = (_Float16*)alloc(NB * N * 512 * sizeof(_Float16));  // [n][q|k]
  _Float16* v = (_Float16*)alloc(NB * CO * N * sizeof(_Float16));     // [c][n]
  size_t base_used = (size_t)(p - (char*)d_ws);

  // per-batch chunk bytes for the sim/attn chain (+padding slack)
  const size_t per_b = (size_t)N * N * 4 + (size_t)N * N * 2 + 2 * N * 4 + 4096;
  int cb = 8;
  while (cb > 1 && base_used + (size_t)cb * per_b > ws_size) cb >>= 1;
  float* simT = (float*)alloc((size_t)cb * N * N * 4);
  _Float16* attnT = (_Float16*)alloc((size_t)cb * N * N * 2);
  float* cmax = (float*)alloc((size_t)cb * N * 4);
  float* cinv = (float*)alloc((size_t)cb * N * 4);

  // 1) weight convert + x transpose-convert
  conv_w<<<dim3(1024 * 512 / 256), 256, 0, stream>>>(Wq, Wk, Wv, Wb);
  conv_xT<<<dim3(64, 16, 8), 256, 0, stream>>>(x, xT);

  // 2) projections (all batches): qkT[n][o] (transposed out), v[c][n] (natural)
  gemm_nt<_Float16, true><<<dim3(16, 4, 8), 256, 0, stream>>>(
      Wb, xT, qkT, 512, 512, 512, 512, 0, (long)(N * CIN), (long)(N * 512));
  gemm_nt<_Float16, false><<<dim3(16, 4, 8), 256, 0, stream>>>(
      Wb + 512 * 512, xT, v, 512, 512, 512, 2048, 0, (long)(N * CIN),
      (long)(CO * N));

  // 3) per-chunk: simT = (kT . qT^T)^T, softmax-over-rows via column stats,
  //    out = attnT . v^T
  for (int b0 = 0; b0 < 8; b0 += cb) {
    const _Float16* kT = qkT + (size_t)b0 * N * 512 + 256;  // [i][c], lda 512
    const _Float16* qT = qkT + (size_t)b0 * N * 512;        // [j][c], ldb 512
    gemm_nt<float, true><<<dim3(16, 16, cb), 256, 0, stream>>>(
        kT, qT, simT, 256, 512, 512, 2048, (long)(N * 512), (long)(N * 512),
        (long)(N * N));
    colstats<<<dim3(32, cb), 256, 0, stream>>>(simT, cmax, cinv);
    attnscale<<<dim3(4096, cb), 256, 0, stream>>>(simT, cmax, cinv, attnT);
    gemm_nt<float, false><<<dim3(4, 16, cb), 256, 0, stream>>>(
        attnT, v + (size_t)b0 * CO * N, out + (size_t)b0 * N * CO, 2048, 2048,
        2048, 512, (long)(N * N), (long)(CO * N), (long)(N * CO));
  }
}

// Round 2
// 311.325 us; speedup vs baseline: 1.6228x; 1.6228x over previous
//
#include <hip/hip_runtime.h>

typedef _Float16 half8 __attribute__((ext_vector_type(8)));
typedef _Float16 half4v __attribute__((ext_vector_type(4)));
typedef float f32x4 __attribute__((ext_vector_type(4)));

static __device__ __forceinline__ f32x4 vmax4(f32x4 a, f32x4 b) {
  f32x4 r;
  r[0] = fmaxf(a[0], b[0]);
  r[1] = fmaxf(a[1], b[1]);
  r[2] = fmaxf(a[2], b[2]);
  r[3] = fmaxf(a[3], b[3]);
  return r;
}

// ---------------------------------------------------------------------------
// Convert Wq||Wk||Wv (fp32 [O,512] each) -> Wb fp16 [1024][512] (c-inner)
// ---------------------------------------------------------------------------
__global__ __launch_bounds__(256) void conv_w(const float* __restrict__ Wq,
                                              const float* __restrict__ Wk,
                                              const float* __restrict__ Wv,
                                              _Float16* __restrict__ Wb) {
  int idx = blockIdx.x * 256 + threadIdx.x;  // 0 .. 1024*512
  int row = idx >> 9;
  float v;
  if (row < 256)      v = Wq[idx];
  else if (row < 512) v = Wk[idx - 256 * 512];
  else                v = Wv[idx - 512 * 512];
  Wb[idx] = (_Float16)v;
}

// ---------------------------------------------------------------------------
// x fp32 [B][512][2048] -> xT fp16 [B][2048][512]   (LDS-tiled transpose)
// ---------------------------------------------------------------------------
__global__ __launch_bounds__(256) void conv_xT(const float* __restrict__ x,
                                               _Float16* __restrict__ xT) {
  __shared__ float T[32][33];
  const int b = blockIdx.z;
  const int n0 = blockIdx.x * 32, c0 = blockIdx.y * 32;
  const int tx = threadIdx.x & 31, ty = threadIdx.x >> 5;  // ty in 0..7
  const float* xb = x + (size_t)b * 512 * 2048;
#pragma unroll
  for (int r = 0; r < 4; r++)
    T[ty + r * 8][tx] = xb[(size_t)(c0 + ty + r * 8) * 2048 + n0 + tx];
  __syncthreads();
  _Float16* xtb = xT + (size_t)b * 2048 * 512;
#pragma unroll
  for (int r = 0; r < 4; r++)
    xtb[(size_t)(n0 + ty + r * 8) * 512 + c0 + tx] = (_Float16)T[tx][ty + r * 8];
}

// ---------------------------------------------------------------------------
// NT-GEMM: C[m][n] = sum_k A[m][k]*B[n][k].  A fp16 [M,K] lda, B fp16 [N,K] ldb.
// Block 256 thr = 4 waves; block tile 128x128; wave tile 64x64 (4x4 MFMAs).
// TR=false: C[m*ldc + n].  TR=true: C[n*ldc + m]  (transposed output).
// Grid: (N/128, M/128, batches). All of M,N mult of 128; K mult of 32.
// ---------------------------------------------------------------------------
template <typename OutT, bool TR>
__global__ __launch_bounds__(256) void gemm_nt(const _Float16* __restrict__ A,
                                               const _Float16* __restrict__ B,
                                               OutT* __restrict__ C, int K,
                                               int lda, int ldb, int ldc,
                                               long sA, long sB, long sC) {
  A += (size_t)blockIdx.z * sA;
  B += (size_t)blockIdx.z * sB;
  C += (size_t)blockIdx.z * sC;
  const int m_blk = blockIdx.y * 128, n_blk = blockIdx.x * 128;

  __shared__ _Float16 As[4096];  // [128 rows][32 k]  (k-inner, 16B frag reads)
  __shared__ _Float16 Bs[4096];

  const int t = threadIdx.x;
  const int lane = t & 63, wave = t >> 6;
  const int quad = lane >> 4, l16 = lane & 15;
  const int wm = (wave & 1) * 64, wn = (wave >> 1) * 64;

  // staging: chunk c covers row c/4, k-offset (c%4)*8; thread t does c=t, c=t+256
  const int r0 = t >> 2, ko = (t & 3) * 8;
  const _Float16* pa0 = A + (size_t)(m_blk + r0) * lda + ko;
  const _Float16* pa1 = A + (size_t)(m_blk + r0 + 64) * lda + ko;
  const _Float16* pb0 = B + (size_t)(n_blk + r0) * ldb + ko;
  const _Float16* pb1 = B + (size_t)(n_blk + r0 + 64) * ldb + ko;

  f32x4 acc[4][4] = {};

  for (int k0 = 0; k0 < K; k0 += 32) {
    uint4 a0 = *(const uint4*)(pa0 + k0);
    uint4 a1 = *(const uint4*)(pa1 + k0);
    uint4 b0 = *(const uint4*)(pb0 + k0);
    uint4 b1 = *(const uint4*)(pb1 + k0);
    __syncthreads();  // previous iter's readers done
    *(uint4*)&As[t * 8] = a0;
    *(uint4*)&As[2048 + t * 8] = a1;
    *(uint4*)&Bs[t * 8] = b0;
    *(uint4*)&Bs[2048 + t * 8] = b1;
    __syncthreads();
    half8 af[4], bf[4];
#pragma unroll
    for (int i = 0; i < 4; i++) {
      af[i] = *(const half8*)&As[(wm + i * 16 + l16) * 32 + quad * 8];
      bf[i] = *(const half8*)&Bs[(wn + i * 16 + l16) * 32 + quad * 8];
    }
#pragma unroll
    for (int i = 0; i < 4; i++)
#pragma unroll
      for (int j = 0; j < 4; j++)
        acc[i][j] =
            __builtin_amdgcn_mfma_f32_16x16x32_f16(af[i], bf[j], acc[i][j], 0, 0, 0);
  }

  // epilogue: D element (row = quad*4 + reg, col = l16) within each 16x16 tile
#pragma unroll
  for (int i = 0; i < 4; i++) {
    const int m0 = m_blk + wm + i * 16 + quad * 4;
#pragma unroll
    for (int j = 0; j < 4; j++) {
      const int n0 = n_blk + wn + j * 16 + l16;
      if constexpr (TR) {
        if constexpr (sizeof(OutT) == 4) {
          *(f32x4*)&C[(size_t)n0 * ldc + m0] = acc[i][j];
        } else {
          half4v h;
          h[0] = (_Float16)acc[i][j][0];
          h[1] = (_Float16)acc[i][j][1];
          h[2] = (_Float16)acc[i][j][2];
          h[3] = (_Float16)acc[i][j][3];
          *(half4v*)&C[(size_t)n0 * ldc + m0] = h;
        }
      } else {
#pragma unroll
        for (int r = 0; r < 4; r++)
          C[(size_t)(m0 + r) * ldc + n0] = (OutT)acc[i][j][r];
      }
    }
  }
}

// ---------------------------------------------------------------------------
// Column-stats stage 1: partial (max, expsum) per column over a 128-row chunk.
// simT [2048 rows][2048 cols]; softmax axis = rows.
// Grid (2048/256 colblocks = 8, 2048/128 rowchunks = 16, nb); block 256.
// Each lane owns 4 consecutive cols (float4); wave reads 1KB contiguous.
// pm/ps layout: [b][rowchunk(16)][2048]
// ---------------------------------------------------------------------------
__global__ __launch_bounds__(256) void colstats1(const float* __restrict__ simT,
                                                 float* __restrict__ pm,
                                                 float* __restrict__ ps) {
  const int b = blockIdx.z;
  const float* S = simT + (size_t)b * 2048 * 2048;
  const int l = threadIdx.x & 63, w = threadIdx.x >> 6;
  const int col = blockIdx.x * 256 + l * 4;
  const int r0 = blockIdx.y * 128;
  __shared__ f32x4 red[4][64];

  // pass 1: block-local column max (rows strided by wave)
  f32x4 m = {-3.0e38f, -3.0e38f, -3.0e38f, -3.0e38f};
#pragma unroll 4
  for (int r = r0 + w; r < r0 + 128; r += 4)
    m = vmax4(m, *(const f32x4*)&S[(size_t)r * 2048 + col]);
  red[w][l] = m;
  __syncthreads();
  f32x4 mb = vmax4(vmax4(red[0][l], red[1][l]), vmax4(red[2][l], red[3][l]));
  __syncthreads();

  // pass 2: expsum vs block max (chunk is 128KB -> L2-hot re-read)
  f32x4 s = {0.f, 0.f, 0.f, 0.f};
#pragma unroll 4
  for (int r = r0 + w; r < r0 + 128; r += 4) {
    f32x4 v = *(const f32x4*)&S[(size_t)r * 2048 + col];
    s[0] += __expf(v[0] - mb[0]);
    s[1] += __expf(v[1] - mb[1]);
    s[2] += __expf(v[2] - mb[2]);
    s[3] += __expf(v[3] - mb[3]);
  }
  red[w][l] = s;
  __syncthreads();
  if (w == 0) {
    f32x4 st = red[0][l] + red[1][l] + red[2][l] + red[3][l];
    size_t o = ((size_t)b * 16 + blockIdx.y) * 2048 + col;
    *(f32x4*)&pm[o] = mb;
    *(f32x4*)&ps[o] = st;
  }
}

// ---------------------------------------------------------------------------
// Column-stats stage 2: merge 16 partials per column -> cmax, cinv.
// Grid (nb*2048/256); one thread per column.
// ---------------------------------------------------------------------------
__global__ __launch_bounds__(256) void colstats2(const float* __restrict__ pm,
                                                 const float* __restrict__ ps,
                                                 float* __restrict__ cmax,
                                                 float* __restrict__ cinv) {
  const int idx = blockIdx.x * 256 + threadIdx.x;  // b*2048 + col
  const int b = idx >> 11, col = idx & 2047;
  const float* pmb = pm + (size_t)b * 16 * 2048 + col;
  const float* psb = ps + (size_t)b * 16 * 2048 + col;
  float m = -3.0e38f;
#pragma unroll
  for (int i = 0; i < 16; i++) m = fmaxf(m, pmb[(size_t)i * 2048]);
  float s = 0.f;
#pragma unroll
  for (int i = 0; i < 16; i++)
    s += psb[(size_t)i * 2048] * __expf(pmb[(size_t)i * 2048] - m);
  cmax[idx] = m;
  cinv[idx] = 1.0f / s;
}

// ---------------------------------------------------------------------------
// attnT[m][k] = fp16( exp(simT[m][k]-cmax[k]) * cinv[k] ).  Grid (4096, nb).
// ---------------------------------------------------------------------------
__global__ __launch_bounds__(256) void attnscale(const float* __restrict__ simT,
                                                 const float* __restrict__ cmax,
                                                 const float* __restrict__ cinv,
                                                 _Float16* __restrict__ attnT) {
  const size_t b = blockIdx.y;
  const size_t g = (size_t)blockIdx.x * 256 + threadIdx.x;  // float4 group
  const int cg = (int)(g & 511);
  f32x4 s = *(const f32x4*)(simT + b * (2048ull * 2048) + g * 4);
  f32x4 mx = *(const f32x4*)(cmax + b * 2048 + cg * 4);
  f32x4 iv = *(const f32x4*)(cinv + b * 2048 + cg * 4);
  half4v h;
  h[0] = (_Float16)(__expf(s[0] - mx[0]) * iv[0]);
  h[1] = (_Float16)(__expf(s[1] - mx[1]) * iv[1]);
  h[2] = (_Float16)(__expf(s[2] - mx[2]) * iv[2]);
  h[3] = (_Float16)(__expf(s[3] - mx[3]) * iv[3]);
  *(half4v*)(attnT + b * (2048ull * 2048) + g * 4) = h;
}

// ---------------------------------------------------------------------------
extern "C" void kernel_launch(void* const* d_in, const int* in_sizes, int n_in,
                              void* d_out, int out_size, void* d_ws,
                              size_t ws_size, hipStream_t stream) {
  const float* x = (const float*)d_in[0];
  const float* Wq = (const float*)d_in[1];
  const float* Wk = (const float*)d_in[2];
  const float* Wv = (const float*)d_in[3];
  float* out = (float*)d_out;

  char* p = (char*)d_ws;
  auto alloc = [&](size_t bytes) -> char* {
    char* r = p;
    p += (bytes + 255) & ~(size_t)255;
    return r;
  };
  const size_t NB = 8, N = 2048, CIN = 512, CK = 256, CO = 512;
  _Float16* Wb = (_Float16*)alloc(1024 * 512 * sizeof(_Float16));
  _Float16* xT = (_Float16*)alloc(NB * N * CIN * sizeof(_Float16));
  _Float16* qkT = (_Float16*)alloc(NB * N * 512 * sizeof(_Float16));  // [n][q|k]
  _Float16* v = (_Float16*)alloc(NB * CO * N * sizeof(_Float16));     // [c][n]
  size_t base_used = (size_t)(p - (char*)d_ws);

  // per-batch chunk bytes for the sim/attn chain (+padding slack)
  const size_t per_b = (size_t)N * N * 4 + (size_t)N * N * 2 + 2 * N * 4 +
                       2 * 16 * N * 4 + 8192;
  int cb = 8;
  while (cb > 1 && base_used + (size_t)cb * per_b > ws_size) cb >>= 1;
  float* simT = (float*)alloc((size_t)cb * N * N * 4);
  _Float16* attnT = (_Float16*)alloc((size_t)cb * N * N * 2);
  float* cmax = (float*)alloc((size_t)cb * N * 4);
  float* cinv = (float*)alloc((size_t)cb * N * 4);
  float* pm = (float*)alloc((size_t)cb * 16 * N * 4);
  float* ps = (float*)alloc((size_t)cb * 16 * N * 4);

  // 1) weight convert + x transpose-convert
  conv_w<<<dim3(1024 * 512 / 256), 256, 0, stream>>>(Wq, Wk, Wv, Wb);
  conv_xT<<<dim3(64, 16, 8), 256, 0, stream>>>(x, xT);

  // 2) projections (all batches): qkT[n][o] (transposed out), v[c][n] (natural)
  gemm_nt<_Float16, true><<<dim3(16, 4, 8), 256, 0, stream>>>(
      Wb, xT, qkT, 512, 512, 512, 512, 0, (long)(N * CIN), (long)(N * 512));
  gemm_nt<_Float16, false><<<dim3(16, 4, 8), 256, 0, stream>>>(
      Wb + 512 * 512, xT, v, 512, 512, 512, 2048, 0, (long)(N * CIN),
      (long)(CO * N));

  // 3) per-chunk: simT = (kT . qT^T)^T, softmax-over-rows via column stats,
  //    out = attnT . v^T
  for (int b0 = 0; b0 < 8; b0 += cb) {
    const _Float16* kT = qkT + (size_t)b0 * N * 512 + 256;  // [i][c], lda 512
    const _Float16* qT = qkT + (size_t)b0 * N * 512;        // [j][c], ldb 512
    gemm_nt<float, true><<<dim3(16, 16, cb), 256, 0, stream>>>(
        kT, qT, simT, 256, 512, 512, 2048, (long)(N * 512), (long)(N * 512),
        (long)(N * N));
    colstats1<<<dim3(8, 16, cb), 256, 0, stream>>>(simT, pm, ps);
    colstats2<<<dim3(cb * 8), 256, 0, stream>>>(pm, ps, cmax, cinv);
    attnscale<<<dim3(4096, cb), 256, 0, stream>>>(simT, cmax, cinv, attnT);
    gemm_nt<float, false><<<dim3(4, 16, cb), 256, 0, stream>>>(
        attnT, v + (size_t)b0 * CO * N, out + (size_t)b0 * N * CO, 2048, 2048,
        2048, 512, (long)(N * N), (long)(CO * N), (long)(N * CO));
  }
}

// Round 3
// 285.077 us; speedup vs baseline: 1.7722x; 1.0921x over previous
//
#include <hip/hip_runtime.h>

typedef _Float16 half8 __attribute__((ext_vector_type(8)));
typedef _Float16 half4v __attribute__((ext_vector_type(4)));
typedef float f32x4 __attribute__((ext_vector_type(4)));

// LDS tile leading-dim pad: 32 -> 40 halves (80 B = 20 banks) so the b128
// frag reads alias at most 2-way (free, m136) instead of 8-way.
#define LDSP 40

// ---------------------------------------------------------------------------
// Convert Wq||Wk||Wv (fp32 [O,512] each) -> Wb fp16 [1024][512] (c-inner)
// ---------------------------------------------------------------------------
__global__ __launch_bounds__(256) void conv_w(const float* __restrict__ Wq,
                                              const float* __restrict__ Wk,
                                              const float* __restrict__ Wv,
                                              _Float16* __restrict__ Wb) {
  int idx = blockIdx.x * 256 + threadIdx.x;  // 0 .. 1024*512
  int row = idx >> 9;
  float v;
  if (row < 256)      v = Wq[idx];
  else if (row < 512) v = Wk[idx - 256 * 512];
  else                v = Wv[idx - 512 * 512];
  Wb[idx] = (_Float16)v;
}

// ---------------------------------------------------------------------------
// x fp32 [B][512][2048] -> xT fp16 [B][2048][512]   (LDS-tiled transpose)
// ---------------------------------------------------------------------------
__global__ __launch_bounds__(256) void conv_xT(const float* __restrict__ x,
                                               _Float16* __restrict__ xT) {
  __shared__ float T[32][33];
  const int b = blockIdx.z;
  const int n0 = blockIdx.x * 32, c0 = blockIdx.y * 32;
  const int tx = threadIdx.x & 31, ty = threadIdx.x >> 5;  // ty in 0..7
  const float* xb = x + (size_t)b * 512 * 2048;
#pragma unroll
  for (int r = 0; r < 4; r++)
    T[ty + r * 8][tx] = xb[(size_t)(c0 + ty + r * 8) * 2048 + n0 + tx];
  __syncthreads();
  _Float16* xtb = xT + (size_t)b * 2048 * 512;
#pragma unroll
  for (int r = 0; r < 4; r++)
    xtb[(size_t)(n0 + ty + r * 8) * 512 + c0 + tx] = (_Float16)T[tx][ty + r * 8];
}

// ---------------------------------------------------------------------------
// NT-GEMM: C[m][n] = sum_k A[m][k]*B[n][k].  A fp16 [M,K] lda, B fp16 [N,K] ldb.
// Block 256 thr = 4 waves; block tile 128x128; wave tile 64x64 (4x4 MFMAs).
// TR=false: C[m*ldc + n].  TR=true: C[n*ldc + m]  (transposed output).
// Grid: (N/128, M/128, batches). All of M,N mult of 128; K mult of 32.
// ---------------------------------------------------------------------------
template <typename OutT, bool TR>
__global__ __launch_bounds__(256) void gemm_nt(const _Float16* __restrict__ A,
                                               const _Float16* __restrict__ B,
                                               OutT* __restrict__ C, int K,
                                               int lda, int ldb, int ldc,
                                               long sA, long sB, long sC) {
  A += (size_t)blockIdx.z * sA;
  B += (size_t)blockIdx.z * sB;
  C += (size_t)blockIdx.z * sC;
  const int m_blk = blockIdx.y * 128, n_blk = blockIdx.x * 128;

  __shared__ _Float16 As[128 * LDSP];  // [128 rows][32 k used, pad to 40]
  __shared__ _Float16 Bs[128 * LDSP];

  const int t = threadIdx.x;
  const int lane = t & 63, wave = t >> 6;
  const int quad = lane >> 4, l16 = lane & 15;
  const int wm = (wave & 1) * 64, wn = (wave >> 1) * 64;

  // staging: thread t covers row t/4, k-offset (t%4)*8; rows r0 and r0+64
  const int r0 = t >> 2, ko = (t & 3) * 8;
  const int st = r0 * LDSP + ko;  // LDS store index
  const _Float16* pa0 = A + (size_t)(m_blk + r0) * lda + ko;
  const _Float16* pa1 = A + (size_t)(m_blk + r0 + 64) * lda + ko;
  const _Float16* pb0 = B + (size_t)(n_blk + r0) * ldb + ko;
  const _Float16* pb1 = B + (size_t)(n_blk + r0 + 64) * ldb + ko;

  f32x4 acc[4][4] = {};

  for (int k0 = 0; k0 < K; k0 += 32) {
    uint4 a0 = *(const uint4*)(pa0 + k0);
    uint4 a1 = *(const uint4*)(pa1 + k0);
    uint4 b0 = *(const uint4*)(pb0 + k0);
    uint4 b1 = *(const uint4*)(pb1 + k0);
    __syncthreads();  // previous iter's readers done
    *(uint4*)&As[st] = a0;
    *(uint4*)&As[st + 64 * LDSP] = a1;
    *(uint4*)&Bs[st] = b0;
    *(uint4*)&Bs[st + 64 * LDSP] = b1;
    __syncthreads();
    half8 af[4], bf[4];
#pragma unroll
    for (int i = 0; i < 4; i++) {
      af[i] = *(const half8*)&As[(wm + i * 16 + l16) * LDSP + quad * 8];
      bf[i] = *(const half8*)&Bs[(wn + i * 16 + l16) * LDSP + quad * 8];
    }
#pragma unroll
    for (int i = 0; i < 4; i++)
#pragma unroll
      for (int j = 0; j < 4; j++)
        acc[i][j] =
            __builtin_amdgcn_mfma_f32_16x16x32_f16(af[i], bf[j], acc[i][j], 0, 0, 0);
  }

  // epilogue: D element (row = quad*4 + reg, col = l16) within each 16x16 tile
#pragma unroll
  for (int i = 0; i < 4; i++) {
    const int m0 = m_blk + wm + i * 16 + quad * 4;
#pragma unroll
    for (int j = 0; j < 4; j++) {
      const int n0 = n_blk + wn + j * 16 + l16;
      if constexpr (TR) {
        if constexpr (sizeof(OutT) == 4) {
          *(f32x4*)&C[(size_t)n0 * ldc + m0] = acc[i][j];
        } else {
          half4v h;
          h[0] = (_Float16)acc[i][j][0];
          h[1] = (_Float16)acc[i][j][1];
          h[2] = (_Float16)acc[i][j][2];
          h[3] = (_Float16)acc[i][j][3];
          *(half4v*)&C[(size_t)n0 * ldc + m0] = h;
        }
      } else {
#pragma unroll
        for (int r = 0; r < 4; r++)
          C[(size_t)(m0 + r) * ldc + n0] = (OutT)acc[i][j][r];
      }
    }
  }
}

// ---------------------------------------------------------------------------
// Column-stats stage 1 on fp16 logits: partial (max, expsum) per column over a
// 128-row chunk of simH [2048 rows][2048 cols]; softmax axis = rows.
// Grid (2048/512 = 4, 2048/128 = 16, nb); block 256 = 4 waves.
// Lane owns 8 consecutive cols (half8, wave reads 1KB contiguous).
// pm/ps layout: [b][rowchunk(16)][2048]
// ---------------------------------------------------------------------------
__global__ __launch_bounds__(256) void colstats1h(const _Float16* __restrict__ S,
                                                  float* __restrict__ pm,
                                                  float* __restrict__ ps) {
  const int b = blockIdx.z;
  const _Float16* Sb = S + (size_t)b * 2048 * 2048;
  const int l = threadIdx.x & 63, w = threadIdx.x >> 6;
  const int col = blockIdx.x * 512 + l * 8;
  const int r0 = blockIdx.y * 128;
  __shared__ float red[4][64][8];

  float m[8];
#pragma unroll
  for (int i = 0; i < 8; i++) m[i] = -3.0e38f;
  for (int r = r0 + w; r < r0 + 128; r += 4) {
    half8 h = *(const half8*)&Sb[(size_t)r * 2048 + col];
#pragma unroll
    for (int i = 0; i < 8; i++) m[i] = fmaxf(m[i], (float)h[i]);
  }
#pragma unroll
  for (int i = 0; i < 8; i++) red[w][l][i] = m[i];
  __syncthreads();
#pragma unroll
  for (int i = 0; i < 8; i++)
    m[i] = fmaxf(fmaxf(red[0][l][i], red[1][l][i]),
                 fmaxf(red[2][l][i], red[3][l][i]));
  __syncthreads();

  float s[8];
#pragma unroll
  for (int i = 0; i < 8; i++) s[i] = 0.f;
  for (int r = r0 + w; r < r0 + 128; r += 4) {  // re-read: 128KB chunk, L2-hot
    half8 h = *(const half8*)&Sb[(size_t)r * 2048 + col];
#pragma unroll
    for (int i = 0; i < 8; i++) s[i] += __expf((float)h[i] - m[i]);
  }
#pragma unroll
  for (int i = 0; i < 8; i++) red[w][l][i] = s[i];
  __syncthreads();
  if (w == 0) {
    size_t o = ((size_t)b * 16 + blockIdx.y) * 2048 + col;
#pragma unroll
    for (int i = 0; i < 8; i++) {
      pm[o + i] = m[i];
      ps[o + i] = red[0][l][i] + red[1][l][i] + red[2][l][i] + red[3][l][i];
    }
  }
}

// ---------------------------------------------------------------------------
// Column-stats stage 2: merge 16 partials -> shift[col] = max + ln(sum), so
// attn weight = exp(x - shift).  Grid (nb*2048/256).
// ---------------------------------------------------------------------------
__global__ __launch_bounds__(256) void colstats2(const float* __restrict__ pm,
                                                 const float* __restrict__ ps,
                                                 float* __restrict__ shift) {
  const int idx = blockIdx.x * 256 + threadIdx.x;  // b*2048 + col
  const int b = idx >> 11, col = idx & 2047;
  const float* pmb = pm + (size_t)b * 16 * 2048 + col;
  const float* psb = ps + (size_t)b * 16 * 2048 + col;
  float m = -3.0e38f;
#pragma unroll
  for (int i = 0; i < 16; i++) m = fmaxf(m, pmb[(size_t)i * 2048]);
  float s = 0.f;
#pragma unroll
  for (int i = 0; i < 16; i++)
    s += psb[(size_t)i * 2048] * __expf(pmb[(size_t)i * 2048] - m);
  shift[idx] = m + __logf(s);
}

// ---------------------------------------------------------------------------
// In-place: simH[m][k] = fp16( exp(simH[m][k] - shift[k]) ).  Per-thread half8.
// Grid (2048, nb).
// ---------------------------------------------------------------------------
__global__ __launch_bounds__(256) void attnscale(_Float16* __restrict__ simH,
                                                 const float* __restrict__ shift) {
  const size_t b = blockIdx.y;
  const size_t g = (size_t)blockIdx.x * 256 + threadIdx.x;  // half8 group
  const int col = (int)(g & 255) * 8;
  _Float16* p = simH + b * (2048ull * 2048) + g * 8;
  half8 h = *(const half8*)p;
  f32x4 s0 = *(const f32x4*)(shift + b * 2048 + col);
  f32x4 s1 = *(const f32x4*)(shift + b * 2048 + col + 4);
  half8 o;
#pragma unroll
  for (int i = 0; i < 4; i++) {
    o[i] = (_Float16)__expf((float)h[i] - s0[i]);
    o[i + 4] = (_Float16)__expf((float)h[i + 4] - s1[i]);
  }
  *(half8*)p = o;
}

// ---------------------------------------------------------------------------
extern "C" void kernel_launch(void* const* d_in, const int* in_sizes, int n_in,
                              void* d_out, int out_size, void* d_ws,
                              size_t ws_size, hipStream_t stream) {
  const float* x = (const float*)d_in[0];
  const float* Wq = (const float*)d_in[1];
  const float* Wk = (const float*)d_in[2];
  const float* Wv = (const float*)d_in[3];
  float* out = (float*)d_out;

  char* p = (char*)d_ws;
  auto alloc = [&](size_t bytes) -> char* {
    char* r = p;
    p += (bytes + 255) & ~(size_t)255;
    return r;
  };
  const size_t NB = 8, N = 2048, CIN = 512, CO = 512;
  _Float16* Wb = (_Float16*)alloc(1024 * 512 * sizeof(_Float16));
  _Float16* xT = (_Float16*)alloc(NB * N * CIN * sizeof(_Float16));
  _Float16* qkT = (_Float16*)alloc(NB * N * 512 * sizeof(_Float16));  // [n][q|k]
  _Float16* v = (_Float16*)alloc(NB * CO * N * sizeof(_Float16));     // [c][n]
  size_t base_used = (size_t)(p - (char*)d_ws);

  // per-batch bytes for the sim chain: fp16 logits + partials + shift + slack
  const size_t per_b =
      (size_t)N * N * 2 + 2 * 16 * N * 4 + N * 4 + 8192;
  int cb = 8;
  while (cb > 1 && base_used + (size_t)cb * per_b > ws_size) cb >>= 1;
  _Float16* simH = (_Float16*)alloc((size_t)cb * N * N * 2);
  float* pm = (float*)alloc((size_t)cb * 16 * N * 4);
  float* ps = (float*)alloc((size_t)cb * 16 * N * 4);
  float* shift = (float*)alloc((size_t)cb * N * 4);

  // 1) weight convert + x transpose-convert
  conv_w<<<dim3(1024 * 512 / 256), 256, 0, stream>>>(Wq, Wk, Wv, Wb);
  conv_xT<<<dim3(64, 16, 8), 256, 0, stream>>>(x, xT);

  // 2) projections (all batches): qkT[n][o] (transposed out), v[c][n] (natural)
  gemm_nt<_Float16, true><<<dim3(16, 4, 8), 256, 0, stream>>>(
      Wb, xT, qkT, 512, 512, 512, 512, 0, (long)(N * CIN), (long)(N * 512));
  gemm_nt<_Float16, false><<<dim3(16, 4, 8), 256, 0, stream>>>(
      Wb + 512 * 512, xT, v, 512, 512, 512, 2048, 0, (long)(N * CIN),
      (long)(CO * N));

  // 3) per-chunk: simH = fp16((kT . qT^T)^T); softmax-over-rows via column
  //    stats + in-place exp; out = attn . v^T
  for (int b0 = 0; b0 < 8; b0 += cb) {
    const _Float16* kT = qkT + (size_t)b0 * N * 512 + 256;  // [i][c], lda 512
    const _Float16* qT = qkT + (size_t)b0 * N * 512;        // [j][c], ldb 512
    gemm_nt<_Float16, true><<<dim3(16, 16, cb), 256, 0, stream>>>(
        kT, qT, simH, 256, 512, 512, 2048, (long)(N * 512), (long)(N * 512),
        (long)(N * N));
    colstats1h<<<dim3(4, 16, cb), 256, 0, stream>>>(simH, pm, ps);
    colstats2<<<dim3(cb * 8), 256, 0, stream>>>(pm, ps, shift);
    attnscale<<<dim3(2048, cb), 256, 0, stream>>>(simH, shift);
    gemm_nt<float, false><<<dim3(4, 16, cb), 256, 0, stream>>>(
        simH, v + (size_t)b0 * CO * N, out + (size_t)b0 * N * CO, 2048, 2048,
        2048, 512, (long)(N * N), (long)(CO * N), (long)(N * CO));
  }
}

// Round 4
// 265.113 us; speedup vs baseline: 1.9057x; 1.0753x over previous
//
#include <hip/hip_runtime.h>

typedef _Float16 half8 __attribute__((ext_vector_type(8)));
typedef _Float16 half4v __attribute__((ext_vector_type(4)));
typedef float f32x4 __attribute__((ext_vector_type(4)));

// async 16B global->LDS copy (HW: LDS dest = wave-uniform base + lane*16)
#define ASYNC_CP16(gp, lp)                                       \
  __builtin_amdgcn_global_load_lds(                              \
      (const __attribute__((address_space(1))) void*)(gp),       \
      (__attribute__((address_space(3))) void*)(lp), 16, 0, 0)

// ---------------------------------------------------------------------------
// Convert Wq||Wk||Wv (fp32 [O,512] each) -> Wb fp16 [1024][512] (c-inner)
// ---------------------------------------------------------------------------
__global__ __launch_bounds__(256) void conv_w(const float* __restrict__ Wq,
                                              const float* __restrict__ Wk,
                                              const float* __restrict__ Wv,
                                              _Float16* __restrict__ Wb) {
  int idx = blockIdx.x * 256 + threadIdx.x;  // 0 .. 1024*512
  int row = idx >> 9;
  float v;
  if (row < 256)      v = Wq[idx];
  else if (row < 512) v = Wk[idx - 256 * 512];
  else                v = Wv[idx - 512 * 512];
  Wb[idx] = (_Float16)v;
}

// ---------------------------------------------------------------------------
// x fp32 [B][512][2048] -> xT fp16 [B][2048][512]   (LDS-tiled transpose)
// ---------------------------------------------------------------------------
__global__ __launch_bounds__(256) void conv_xT(const float* __restrict__ x,
                                               _Float16* __restrict__ xT) {
  __shared__ float T[32][33];
  const int b = blockIdx.z;
  const int n0 = blockIdx.x * 32, c0 = blockIdx.y * 32;
  const int tx = threadIdx.x & 31, ty = threadIdx.x >> 5;  // ty in 0..7
  const float* xb = x + (size_t)b * 512 * 2048;
#pragma unroll
  for (int r = 0; r < 4; r++)
    T[ty + r * 8][tx] = xb[(size_t)(c0 + ty + r * 8) * 2048 + n0 + tx];
  __syncthreads();
  _Float16* xtb = xT + (size_t)b * 2048 * 512;
#pragma unroll
  for (int r = 0; r < 4; r++)
    xtb[(size_t)(n0 + ty + r * 8) * 512 + c0 + tx] = (_Float16)T[tx][ty + r * 8];
}

// ---------------------------------------------------------------------------
// NT-GEMM: C[m][n] = sum_k A[m][k]*B[n][k].  A fp16 [M,K] lda, B fp16 [N,K] ldb.
// Block 256 thr = 4 waves; block tile 128x128; wave tile 64x64 (4x4 MFMAs).
// Staging: global_load_lds width=16, lane-linear LDS burst; bank-conflict-free
// frag reads via XOR swizzle done on the GLOBAL source side:
//   LDS slot (row r, 16B-chunk c') holds global chunk c' ^ ((r>>1)&3).
// TR=false: C[m*ldc + n].  TR=true: C[n*ldc + m]  (transposed output).
// Grid: (N/128, M/128, batches). M,N mult of 128; K mult of 32; ld* mult of 8.
// ---------------------------------------------------------------------------
template <typename OutT, bool TR>
__global__ __launch_bounds__(256) void gemm_nt(const _Float16* __restrict__ A,
                                               const _Float16* __restrict__ B,
                                               OutT* __restrict__ C, int K,
                                               int lda, int ldb, int ldc,
                                               long sA, long sB, long sC) {
  A += (size_t)blockIdx.z * sA;
  B += (size_t)blockIdx.z * sB;
  C += (size_t)blockIdx.z * sC;
  const int m_blk = blockIdx.y * 128, n_blk = blockIdx.x * 128;

  __shared__ _Float16 As[4096];  // [128 rows][32 k halves] = 8 KB
  __shared__ _Float16 Bs[4096];

  const int t = threadIdx.x;
  const int lane = t & 63, wave = t >> 6;
  const int quad = lane >> 4, l16 = lane & 15;
  const int wm = (wave & 1) * 64, wn = (wave >> 1) * 64;

  // --- staging addressing ---
  // wave w owns LDS rows [16w,16w+16) and [64+16w, 64+16w+16) of each buffer;
  // lane l -> row 16w + (l>>2), fetches swizzled global chunk:
  const int srow = 16 * wave + (lane >> 2);
  const int schunk = (lane & 3) ^ ((lane >> 3) & 3);  // XOR swizzle
  const _Float16* gA0 = A + (size_t)(m_blk + srow) * lda + schunk * 8;
  const _Float16* gA1 = gA0 + (size_t)64 * lda;
  const _Float16* gB0 = B + (size_t)(n_blk + srow) * ldb + schunk * 8;
  const _Float16* gB1 = gB0 + (size_t)64 * ldb;
  _Float16* lA0 = &As[wave * 512 + lane * 8];  // bytes: wave*1024 + lane*16
  _Float16* lA1 = lA0 + 2048;
  _Float16* lB0 = &Bs[wave * 512 + lane * 8];
  _Float16* lB1 = lB0 + 2048;

  // --- frag-read addressing (undo swizzle: chunk = quad ^ ((l16>>1)&3)) ---
  const int rchunk = (quad ^ ((l16 >> 1) & 3)) * 8;

  f32x4 acc[4][4] = {};

  for (int k0 = 0; k0 < K; k0 += 32) {
    if (k0) __syncthreads();  // previous tile's readers done
    ASYNC_CP16(gA0 + k0, lA0);
    ASYNC_CP16(gA1 + k0, lA1);
    ASYNC_CP16(gB0 + k0, lB0);
    ASYNC_CP16(gB1 + k0, lB1);
    __syncthreads();  // drain vmcnt + publish
    half8 af[4], bf[4];
#pragma unroll
    for (int i = 0; i < 4; i++) {
      af[i] = *(const half8*)&As[(wm + i * 16 + l16) * 32 + rchunk];
      bf[i] = *(const half8*)&Bs[(wn + i * 16 + l16) * 32 + rchunk];
    }
#pragma unroll
    for (int i = 0; i < 4; i++)
#pragma unroll
      for (int j = 0; j < 4; j++)
        acc[i][j] =
            __builtin_amdgcn_mfma_f32_16x16x32_f16(af[i], bf[j], acc[i][j], 0, 0, 0);
  }

  // epilogue: D element (row = quad*4 + reg, col = l16) within each 16x16 tile
#pragma unroll
  for (int i = 0; i < 4; i++) {
    const int m0 = m_blk + wm + i * 16 + quad * 4;
#pragma unroll
    for (int j = 0; j < 4; j++) {
      const int n0 = n_blk + wn + j * 16 + l16;
      if constexpr (TR) {
        if constexpr (sizeof(OutT) == 4) {
          *(f32x4*)&C[(size_t)n0 * ldc + m0] = acc[i][j];
        } else {
          half4v h;
          h[0] = (_Float16)acc[i][j][0];
          h[1] = (_Float16)acc[i][j][1];
          h[2] = (_Float16)acc[i][j][2];
          h[3] = (_Float16)acc[i][j][3];
          *(half4v*)&C[(size_t)n0 * ldc + m0] = h;
        }
      } else {
#pragma unroll
        for (int r = 0; r < 4; r++)
          C[(size_t)(m0 + r) * ldc + n0] = (OutT)acc[i][j][r];
      }
    }
  }
}

// ---------------------------------------------------------------------------
// Column-stats stage 1 on fp16 logits: partial (max, expsum) per column over a
// 128-row chunk of simH [2048 rows][2048 cols]; softmax axis = rows.
// Grid (4, 16, nb); block 256 = 4 waves. Lane owns 8 consecutive cols.
// pm/ps layout: [b][rowchunk(16)][2048]
// ---------------------------------------------------------------------------
__global__ __launch_bounds__(256) void colstats1h(const _Float16* __restrict__ S,
                                                  float* __restrict__ pm,
                                                  float* __restrict__ ps) {
  const int b = blockIdx.z;
  const _Float16* Sb = S + (size_t)b * 2048 * 2048;
  const int l = threadIdx.x & 63, w = threadIdx.x >> 6;
  const int col = blockIdx.x * 512 + l * 8;
  const int r0 = blockIdx.y * 128;
  __shared__ float red[4][64][8];

  float m[8];
#pragma unroll
  for (int i = 0; i < 8; i++) m[i] = -3.0e38f;
  for (int r = r0 + w; r < r0 + 128; r += 4) {
    half8 h = *(const half8*)&Sb[(size_t)r * 2048 + col];
#pragma unroll
    for (int i = 0; i < 8; i++) m[i] = fmaxf(m[i], (float)h[i]);
  }
#pragma unroll
  for (int i = 0; i < 8; i++) red[w][l][i] = m[i];
  __syncthreads();
#pragma unroll
  for (int i = 0; i < 8; i++)
    m[i] = fmaxf(fmaxf(red[0][l][i], red[1][l][i]),
                 fmaxf(red[2][l][i], red[3][l][i]));
  __syncthreads();

  float s[8];
#pragma unroll
  for (int i = 0; i < 8; i++) s[i] = 0.f;
  for (int r = r0 + w; r < r0 + 128; r += 4) {  // re-read: 128KB chunk, L2-hot
    half8 h = *(const half8*)&Sb[(size_t)r * 2048 + col];
#pragma unroll
    for (int i = 0; i < 8; i++) s[i] += __expf((float)h[i] - m[i]);
  }
#pragma unroll
  for (int i = 0; i < 8; i++) red[w][l][i] = s[i];
  __syncthreads();
  if (w == 0) {
    size_t o = ((size_t)b * 16 + blockIdx.y) * 2048 + col;
#pragma unroll
    for (int i = 0; i < 8; i++) {
      pm[o + i] = m[i];
      ps[o + i] = red[0][l][i] + red[1][l][i] + red[2][l][i] + red[3][l][i];
    }
  }
}

// ---------------------------------------------------------------------------
// Column-stats stage 2: merge 16 partials -> shift[col] = max + ln(sum), so
// attn weight = exp(x - shift).  Grid (nb*2048/256).
// ---------------------------------------------------------------------------
__global__ __launch_bounds__(256) void colstats2(const float* __restrict__ pm,
                                                 const float* __restrict__ ps,
                                                 float* __restrict__ shift) {
  const int idx = blockIdx.x * 256 + threadIdx.x;  // b*2048 + col
  const int b = idx >> 11, col = idx & 2047;
  const float* pmb = pm + (size_t)b * 16 * 2048 + col;
  const float* psb = ps + (size_t)b * 16 * 2048 + col;
  float m = -3.0e38f;
#pragma unroll
  for (int i = 0; i < 16; i++) m = fmaxf(m, pmb[(size_t)i * 2048]);
  float s = 0.f;
#pragma unroll
  for (int i = 0; i < 16; i++)
    s += psb[(size_t)i * 2048] * __expf(pmb[(size_t)i * 2048] - m);
  shift[idx] = m + __logf(s);
}

// ---------------------------------------------------------------------------
// In-place: simH[m][k] = fp16( exp(simH[m][k] - shift[k]) ).  Per-thread half8.
// Grid (2048, nb).
// ---------------------------------------------------------------------------
__global__ __launch_bounds__(256) void attnscale(_Float16* __restrict__ simH,
                                                 const float* __restrict__ shift) {
  const size_t b = blockIdx.y;
  const size_t g = (size_t)blockIdx.x * 256 + threadIdx.x;  // half8 group
  const int col = (int)(g & 255) * 8;
  _Float16* p = simH + b * (2048ull * 2048) + g * 8;
  half8 h = *(const half8*)p;
  f32x4 s0 = *(const f32x4*)(shift + b * 2048 + col);
  f32x4 s1 = *(const f32x4*)(shift + b * 2048 + col + 4);
  half8 o;
#pragma unroll
  for (int i = 0; i < 4; i++) {
    o[i] = (_Float16)__expf((float)h[i] - s0[i]);
    o[i + 4] = (_Float16)__expf((float)h[i + 4] - s1[i]);
  }
  *(half8*)p = o;
}

// ---------------------------------------------------------------------------
extern "C" void kernel_launch(void* const* d_in, const int* in_sizes, int n_in,
                              void* d_out, int out_size, void* d_ws,
                              size_t ws_size, hipStream_t stream) {
  const float* x = (const float*)d_in[0];
  const float* Wq = (const float*)d_in[1];
  const float* Wk = (const float*)d_in[2];
  const float* Wv = (const float*)d_in[3];
  float* out = (float*)d_out;

  char* p = (char*)d_ws;
  auto alloc = [&](size_t bytes) -> char* {
    char* r = p;
    p += (bytes + 255) & ~(size_t)255;
    return r;
  };
  const size_t NB = 8, N = 2048, CIN = 512, CO = 512;
  _Float16* Wb = (_Float16*)alloc(1024 * 512 * sizeof(_Float16));
  _Float16* xT = (_Float16*)alloc(NB * N * CIN * sizeof(_Float16));
  _Float16* qkT = (_Float16*)alloc(NB * N * 512 * sizeof(_Float16));  // [n][q|k]
  _Float16* v = (_Float16*)alloc(NB * CO * N * sizeof(_Float16));     // [c][n]
  size_t base_used = (size_t)(p - (char*)d_ws);

  // per-batch bytes for the sim chain: fp16 logits + partials + shift + slack
  const size_t per_b =
      (size_t)N * N * 2 + 2 * 16 * N * 4 + N * 4 + 8192;
  int cb = 8;
  while (cb > 1 && base_used + (size_t)cb * per_b > ws_size) cb >>= 1;
  _Float16* simH = (_Float16*)alloc((size_t)cb * N * N * 2);
  float* pm = (float*)alloc((size_t)cb * 16 * N * 4);
  float* ps = (float*)alloc((size_t)cb * 16 * N * 4);
  float* shift = (float*)alloc((size_t)cb * N * 4);

  // 1) weight convert + x transpose-convert
  conv_w<<<dim3(1024 * 512 / 256), 256, 0, stream>>>(Wq, Wk, Wv, Wb);
  conv_xT<<<dim3(64, 16, 8), 256, 0, stream>>>(x, xT);

  // 2) projections (all batches): qkT[n][o] (transposed out), v[c][n] (natural)
  gemm_nt<_Float16, true><<<dim3(16, 4, 8), 256, 0, stream>>>(
      Wb, xT, qkT, 512, 512, 512, 512, 0, (long)(N * CIN), (long)(N * 512));
  gemm_nt<_Float16, false><<<dim3(16, 4, 8), 256, 0, stream>>>(
      Wb + 512 * 512, xT, v, 512, 512, 512, 2048, 0, (long)(N * CIN),
      (long)(CO * N));

  // 3) per-chunk: simH = fp16((kT . qT^T)^T); softmax-over-rows via column
  //    stats + in-place exp; out = attn . v^T
  for (int b0 = 0; b0 < 8; b0 += cb) {
    const _Float16* kT = qkT + (size_t)b0 * N * 512 + 256;  // [i][c], lda 512
    const _Float16* qT = qkT + (size_t)b0 * N * 512;        // [j][c], ldb 512
    gemm_nt<_Float16, true><<<dim3(16, 16, cb), 256, 0, stream>>>(
        kT, qT, simH, 256, 512, 512, 2048, (long)(N * 512), (long)(N * 512),
        (long)(N * N));
    colstats1h<<<dim3(4, 16, cb), 256, 0, stream>>>(simH, pm, ps);
    colstats2<<<dim3(cb * 8), 256, 0, stream>>>(pm, ps, shift);
    attnscale<<<dim3(2048, cb), 256, 0, stream>>>(simH, shift);
    gemm_nt<float, false><<<dim3(4, 16, cb), 256, 0, stream>>>(
        simH, v + (size_t)b0 * CO * N, out + (size_t)b0 * N * CO, 2048, 2048,
        2048, 512, (long)(N * N), (long)(CO * N), (long)(N * CO));
  }
}

// Round 5
// 241.208 us; speedup vs baseline: 2.0946x; 1.0991x over previous
//
#include <hip/hip_runtime.h>

typedef _Float16 half8 __attribute__((ext_vector_type(8)));
typedef _Float16 half4v __attribute__((ext_vector_type(4)));
typedef _Float16 half2v __attribute__((ext_vector_type(2)));
typedef float f32x4 __attribute__((ext_vector_type(4)));

// async 16B global->LDS copy (HW: LDS dest = wave-uniform base + lane*16)
#define ASYNC_CP16(gp, lp)                                       \
  __builtin_amdgcn_global_load_lds(                              \
      (const __attribute__((address_space(1))) void*)(gp),       \
      (__attribute__((address_space(3))) void*)(lp), 16, 0, 0)

// ---------------------------------------------------------------------------
// Convert Wq||Wk||Wv (fp32 [O,512] each) -> Wb fp16 [1024][512] (c-inner)
// ---------------------------------------------------------------------------
__global__ __launch_bounds__(256) void conv_w(const float* __restrict__ Wq,
                                              const float* __restrict__ Wk,
                                              const float* __restrict__ Wv,
                                              _Float16* __restrict__ Wb) {
  int idx = blockIdx.x * 256 + threadIdx.x;  // 0 .. 1024*512
  int row = idx >> 9;
  float v;
  if (row < 256)      v = Wq[idx];
  else if (row < 512) v = Wk[idx - 256 * 512];
  else                v = Wv[idx - 512 * 512];
  Wb[idx] = (_Float16)v;
}

// ---------------------------------------------------------------------------
// x fp32 [B][512][2048] -> xT fp16 [B][2048][512]   (LDS-tiled transpose)
// float2 loads / half2 stores; 33-pitch keeps all LDS phases <=2-way (free).
// ---------------------------------------------------------------------------
__global__ __launch_bounds__(256) void conv_xT(const float* __restrict__ x,
                                               _Float16* __restrict__ xT) {
  __shared__ float T[32][33];
  const int b = blockIdx.z;
  const int n0 = blockIdx.x * 32, c0 = blockIdx.y * 32;
  const int t = threadIdx.x;
  const float* xb = x + (size_t)b * 512 * 2048;
  const int n2 = t & 15, cr = t >> 4;  // load: 16 float2-cols x 16 c-rows
#pragma unroll
  for (int r = 0; r < 2; r++) {
    int c = cr + r * 16;
    float2 v = *(const float2*)&xb[(size_t)(c0 + c) * 2048 + n0 + n2 * 2];
    T[c][n2 * 2] = v.x;
    T[c][n2 * 2 + 1] = v.y;
  }
  __syncthreads();
  _Float16* xtb = xT + (size_t)b * 2048 * 512;
  const int c2 = t & 15, nr = t >> 4;  // store: 16 half2-cols x 16 n-rows
#pragma unroll
  for (int r = 0; r < 2; r++) {
    int n = nr + r * 16;
    half2v h;
    h[0] = (_Float16)T[c2 * 2][n];
    h[1] = (_Float16)T[c2 * 2 + 1][n];
    *(half2v*)&xtb[(size_t)(n0 + n) * 512 + c0 + c2 * 2] = h;
  }
}

// ---------------------------------------------------------------------------
// NT-GEMM: C[m][n] = sum_k A[m][k]*B[n][k].  A fp16 [M,K] lda, B fp16 [N,K] ldb.
// Block 256 thr = 4 waves; block tile 128x128; wave tile 64x64 (4x4 MFMAs).
// Double-buffered async staging (global_load_lds w=16), ONE barrier per iter:
// prefetch tile k+1 into buf^1 right after the barrier, compute tile k.
// Bank-conflict-free frag reads via XOR swizzle on the GLOBAL source side:
//   LDS slot (row r, 16B-chunk c') holds global chunk c' ^ ((r>>1)&3).
// TR=false: C[m*ldc + n].  TR=true: C[n*ldc + m]  (transposed output).
// STATS (requires TR): also emit per-column-of-C (per m) partial softmax
// stats over this block's 128 n's: pm/ps[b][blockIdx.x][m].
// Grid: (N/128, M/128, batches). M,N mult of 128; K mult of 32; ld* mult of 8.
// ---------------------------------------------------------------------------
template <typename OutT, bool TR, bool STATS>
__global__ __launch_bounds__(256) void gemm_nt(const _Float16* __restrict__ A,
                                               const _Float16* __restrict__ B,
                                               OutT* __restrict__ C, int K,
                                               int lda, int ldb, int ldc,
                                               long sA, long sB, long sC,
                                               float* __restrict__ pm,
                                               float* __restrict__ ps) {
  A += (size_t)blockIdx.z * sA;
  B += (size_t)blockIdx.z * sB;
  C += (size_t)blockIdx.z * sC;
  const int m_blk = blockIdx.y * 128, n_blk = blockIdx.x * 128;

  __shared__ _Float16 As[2][4096];  // [buf][128 rows][32 k halves]
  __shared__ _Float16 Bs[2][4096];

  const int t = threadIdx.x;
  const int lane = t & 63, wave = t >> 6;
  const int quad = lane >> 4, l16 = lane & 15;
  const int wm = (wave & 1) * 64, wn = (wave >> 1) * 64;

  // --- staging addressing ---
  // wave w owns LDS rows [16w,16w+16) and [64+16w,64+16w+16) of each buffer;
  // lane l -> row 16w + (l>>2), fetches swizzled global chunk:
  const int srow = 16 * wave + (lane >> 2);
  const int schunk = (lane & 3) ^ ((lane >> 3) & 3);  // XOR swizzle
  const _Float16* gA0 = A + (size_t)(m_blk + srow) * lda + schunk * 8;
  const _Float16* gA1 = gA0 + (size_t)64 * lda;
  const _Float16* gB0 = B + (size_t)(n_blk + srow) * ldb + schunk * 8;
  const _Float16* gB1 = gB0 + (size_t)64 * ldb;
  const int lofs = wave * 512 + lane * 8;  // halves within one buffer

  // --- frag-read addressing (undo swizzle: chunk = quad ^ ((l16>>1)&3)) ---
  const int rchunk = (quad ^ ((l16 >> 1) & 3)) * 8;

  f32x4 acc[4][4] = {};

  // prologue: stage tile 0 into buffer 0
  ASYNC_CP16(gA0, &As[0][lofs]);
  ASYNC_CP16(gA1, &As[0][lofs + 2048]);
  ASYNC_CP16(gB0, &Bs[0][lofs]);
  ASYNC_CP16(gB1, &Bs[0][lofs + 2048]);

  int ib = 0;
  for (int k0 = 0; k0 < K; k0 += 32, ib ^= 1) {
    __syncthreads();  // buf ib's copies landed; prev readers of buf ib^1 done
    if (k0 + 32 < K) {  // prefetch next tile into the other buffer
      ASYNC_CP16(gA0 + k0 + 32, &As[ib ^ 1][lofs]);
      ASYNC_CP16(gA1 + k0 + 32, &As[ib ^ 1][lofs + 2048]);
      ASYNC_CP16(gB0 + k0 + 32, &Bs[ib ^ 1][lofs]);
      ASYNC_CP16(gB1 + k0 + 32, &Bs[ib ^ 1][lofs + 2048]);
    }
    half8 af[4], bf[4];
#pragma unroll
    for (int i = 0; i < 4; i++) {
      af[i] = *(const half8*)&As[ib][(wm + i * 16 + l16) * 32 + rchunk];
      bf[i] = *(const half8*)&Bs[ib][(wn + i * 16 + l16) * 32 + rchunk];
    }
#pragma unroll
    for (int i = 0; i < 4; i++)
#pragma unroll
      for (int j = 0; j < 4; j++)
        acc[i][j] =
            __builtin_amdgcn_mfma_f32_16x16x32_f16(af[i], bf[j], acc[i][j], 0, 0, 0);
  }

  // epilogue: D element (row = quad*4 + reg, col = l16) within each 16x16 tile
#pragma unroll
  for (int i = 0; i < 4; i++) {
    const int m0 = m_blk + wm + i * 16 + quad * 4;
#pragma unroll
    for (int j = 0; j < 4; j++) {
      const int n0 = n_blk + wn + j * 16 + l16;
      if constexpr (TR) {
        if constexpr (sizeof(OutT) == 4) {
          *(f32x4*)&C[(size_t)n0 * ldc + m0] = acc[i][j];
        } else {
          half4v h;
          h[0] = (_Float16)acc[i][j][0];
          h[1] = (_Float16)acc[i][j][1];
          h[2] = (_Float16)acc[i][j][2];
          h[3] = (_Float16)acc[i][j][3];
          *(half4v*)&C[(size_t)n0 * ldc + m0] = h;
        }
      } else {
#pragma unroll
        for (int r = 0; r < 4; r++)
          C[(size_t)(m0 + r) * ldc + n0] = (OutT)acc[i][j][r];
      }
    }
  }

  // fused partial softmax stats (per gemm-m, over this block's 128 n's)
  if constexpr (STATS) {
    __shared__ float sred[2][128][2];  // [n-half][m_local][max|sum]
    const int wng = wave >> 1;         // which 64-n half this wave covers
    float bmax[4][4], bsum[4][4];
#pragma unroll
    for (int i = 0; i < 4; i++) {
#pragma unroll
      for (int r = 0; r < 4; r++) {
        float mx = acc[i][0][r];
#pragma unroll
        for (int j = 1; j < 4; j++) mx = fmaxf(mx, acc[i][j][r]);
#pragma unroll
        for (int d = 1; d < 16; d <<= 1)
          mx = fmaxf(mx, __shfl_xor(mx, d, 64));
        float es = 0.f;
#pragma unroll
        for (int j = 0; j < 4; j++) es += __expf(acc[i][j][r] - mx);
#pragma unroll
        for (int d = 1; d < 16; d <<= 1) es += __shfl_xor(es, d, 64);
        bmax[i][r] = mx;
        bsum[i][r] = es;
      }
    }
    if (l16 == 0) {
#pragma unroll
      for (int i = 0; i < 4; i++)
#pragma unroll
        for (int r = 0; r < 4; r++) {
          int ml = wm + i * 16 + quad * 4 + r;
          sred[wng][ml][0] = bmax[i][r];
          sred[wng][ml][1] = bsum[i][r];
        }
    }
    __syncthreads();
    if (t < 128) {
      float m0 = sred[0][t][0], s0 = sred[0][t][1];
      float m1 = sred[1][t][0], s1 = sred[1][t][1];
      float M = fmaxf(m0, m1);
      float S = s0 * __expf(m0 - M) + s1 * __expf(m1 - M);
      size_t o = ((size_t)blockIdx.z * 16 + blockIdx.x) * 2048 + m_blk + t;
      pm[o] = M;
      ps[o] = S;
    }
  }
}

// ---------------------------------------------------------------------------
// Column-stats stage 2: merge 16 partials -> shift[col] = max + ln(sum), so
// attn weight = exp(x - shift).  Grid (nb*2048/256).
// ---------------------------------------------------------------------------
__global__ __launch_bounds__(256) void colstats2(const float* __restrict__ pm,
                                                 const float* __restrict__ ps,
                                                 float* __restrict__ shift) {
  const int idx = blockIdx.x * 256 + threadIdx.x;  // b*2048 + col
  const int b = idx >> 11, col = idx & 2047;
  const float* pmb = pm + (size_t)b * 16 * 2048 + col;
  const float* psb = ps + (size_t)b * 16 * 2048 + col;
  float m = -3.0e38f;
#pragma unroll
  for (int i = 0; i < 16; i++) m = fmaxf(m, pmb[(size_t)i * 2048]);
  float s = 0.f;
#pragma unroll
  for (int i = 0; i < 16; i++)
    s += psb[(size_t)i * 2048] * __expf(pmb[(size_t)i * 2048] - m);
  shift[idx] = m + __logf(s);
}

// ---------------------------------------------------------------------------
// In-place: simH[m][k] = fp16( exp(simH[m][k] - shift[k]) ).  Per-thread half8.
// Grid (2048, nb).
// ---------------------------------------------------------------------------
__global__ __launch_bounds__(256) void attnscale(_Float16* __restrict__ simH,
                                                 const float* __restrict__ shift) {
  const size_t b = blockIdx.y;
  const size_t g = (size_t)blockIdx.x * 256 + threadIdx.x;  // half8 group
  const int col = (int)(g & 255) * 8;
  _Float16* p = simH + b * (2048ull * 2048) + g * 8;
  half8 h = *(const half8*)p;
  f32x4 s0 = *(const f32x4*)(shift + b * 2048 + col);
  f32x4 s1 = *(const f32x4*)(shift + b * 2048 + col + 4);
  half8 o;
#pragma unroll
  for (int i = 0; i < 4; i++) {
    o[i] = (_Float16)__expf((float)h[i] - s0[i]);
    o[i + 4] = (_Float16)__expf((float)h[i + 4] - s1[i]);
  }
  *(half8*)p = o;
}

// ---------------------------------------------------------------------------
extern "C" void kernel_launch(void* const* d_in, const int* in_sizes, int n_in,
                              void* d_out, int out_size, void* d_ws,
                              size_t ws_size, hipStream_t stream) {
  const float* x = (const float*)d_in[0];
  const float* Wq = (const float*)d_in[1];
  const float* Wk = (const float*)d_in[2];
  const float* Wv = (const float*)d_in[3];
  float* out = (float*)d_out;

  char* p = (char*)d_ws;
  auto alloc = [&](size_t bytes) -> char* {
    char* r = p;
    p += (bytes + 255) & ~(size_t)255;
    return r;
  };
  const size_t NB = 8, N = 2048, CIN = 512, CO = 512;
  _Float16* Wb = (_Float16*)alloc(1024 * 512 * sizeof(_Float16));
  _Float16* xT = (_Float16*)alloc(NB * N * CIN * sizeof(_Float16));
  _Float16* qkT = (_Float16*)alloc(NB * N * 512 * sizeof(_Float16));  // [n][q|k]
  _Float16* v = (_Float16*)alloc(NB * CO * N * sizeof(_Float16));     // [c][n]
  size_t base_used = (size_t)(p - (char*)d_ws);

  // per-batch bytes for the sim chain: fp16 logits + partials + shift + slack
  const size_t per_b =
      (size_t)N * N * 2 + 2 * 16 * N * 4 + N * 4 + 8192;
  int cb = 8;
  while (cb > 1 && base_used + (size_t)cb * per_b > ws_size) cb >>= 1;
  _Float16* simH = (_Float16*)alloc((size_t)cb * N * N * 2);
  float* pm = (float*)alloc((size_t)cb * 16 * N * 4);
  float* ps = (float*)alloc((size_t)cb * 16 * N * 4);
  float* shift = (float*)alloc((size_t)cb * N * 4);

  // 1) weight convert + x transpose-convert
  conv_w<<<dim3(1024 * 512 / 256), 256, 0, stream>>>(Wq, Wk, Wv, Wb);
  conv_xT<<<dim3(64, 16, 8), 256, 0, stream>>>(x, xT);

  // 2) projections (all batches): qkT[n][o] (transposed out), v[c][n] (natural)
  gemm_nt<_Float16, true, false><<<dim3(16, 4, 8), 256, 0, stream>>>(
      Wb, xT, qkT, 512, 512, 512, 512, 0, (long)(N * CIN), (long)(N * 512),
      nullptr, nullptr);
  gemm_nt<_Float16, false, false><<<dim3(16, 4, 8), 256, 0, stream>>>(
      Wb + 512 * 512, xT, v, 512, 512, 512, 2048, 0, (long)(N * CIN),
      (long)(CO * N), nullptr, nullptr);

  // 3) per-chunk: simH = fp16((kT . qT^T)^T) with fused softmax partials;
  //    merge stats; in-place exp; out = attn . v^T
  for (int b0 = 0; b0 < 8; b0 += cb) {
    const _Float16* kT = qkT + (size_t)b0 * N * 512 + 256;  // [i][c], lda 512
    const _Float16* qT = qkT + (size_t)b0 * N * 512;        // [j][c], ldb 512
    gemm_nt<_Float16, true, true><<<dim3(16, 16, cb), 256, 0, stream>>>(
        kT, qT, simH, 256, 512, 512, 2048, (long)(N * 512), (long)(N * 512),
        (long)(N * N), pm, ps);
    colstats2<<<dim3(cb * 8), 256, 0, stream>>>(pm, ps, shift);
    attnscale<<<dim3(2048, cb), 256, 0, stream>>>(simH, shift);
    gemm_nt<float, false, false><<<dim3(4, 16, cb), 256, 0, stream>>>(
        simH, v + (size_t)b0 * CO * N, out + (size_t)b0 * N * CO, 2048, 2048,
        2048, 512, (long)(N * N), (long)(CO * N), (long)(N * CO), nullptr,
        nullptr);
  }
}

// Round 6
// 239.239 us; speedup vs baseline: 2.1118x; 1.0082x over previous
//
#include <hip/hip_runtime.h>

typedef _Float16 half8 __attribute__((ext_vector_type(8)));
typedef _Float16 half4v __attribute__((ext_vector_type(4)));
typedef _Float16 half2v __attribute__((ext_vector_type(2)));
typedef float f32x4 __attribute__((ext_vector_type(4)));

// async 16B global->LDS copy (HW: LDS dest = wave-uniform base + lane*16)
#define ASYNC_CP16(gp, lp)                                       \
  __builtin_amdgcn_global_load_lds(                              \
      (const __attribute__((address_space(1))) void*)(gp),       \
      (__attribute__((address_space(3))) void*)(lp), 16, 0, 0)

// ---------------------------------------------------------------------------
// Convert Wq||Wk||Wv (fp32 [O,512] each) -> Wb fp16 [1024][512] (c-inner)
// ---------------------------------------------------------------------------
__global__ __launch_bounds__(256) void conv_w(const float* __restrict__ Wq,
                                              const float* __restrict__ Wk,
                                              const float* __restrict__ Wv,
                                              _Float16* __restrict__ Wb) {
  int idx = blockIdx.x * 256 + threadIdx.x;  // 0 .. 1024*512
  int row = idx >> 9;
  float v;
  if (row < 256)      v = Wq[idx];
  else if (row < 512) v = Wk[idx - 256 * 512];
  else                v = Wv[idx - 512 * 512];
  Wb[idx] = (_Float16)v;
}

// ---------------------------------------------------------------------------
// x fp32 [B][512][2048] -> xT fp16 [B][2048][512]   (LDS-tiled transpose)
// ---------------------------------------------------------------------------
__global__ __launch_bounds__(256) void conv_xT(const float* __restrict__ x,
                                               _Float16* __restrict__ xT) {
  __shared__ float T[32][33];
  const int b = blockIdx.z;
  const int n0 = blockIdx.x * 32, c0 = blockIdx.y * 32;
  const int t = threadIdx.x;
  const float* xb = x + (size_t)b * 512 * 2048;
  const int n2 = t & 15, cr = t >> 4;  // load: 16 float2-cols x 16 c-rows
#pragma unroll
  for (int r = 0; r < 2; r++) {
    int c = cr + r * 16;
    float2 v = *(const float2*)&xb[(size_t)(c0 + c) * 2048 + n0 + n2 * 2];
    T[c][n2 * 2] = v.x;
    T[c][n2 * 2 + 1] = v.y;
  }
  __syncthreads();
  _Float16* xtb = xT + (size_t)b * 2048 * 512;
  const int c2 = t & 15, nr = t >> 4;  // store: 16 half2-cols x 16 n-rows
#pragma unroll
  for (int r = 0; r < 2; r++) {
    int n = nr + r * 16;
    half2v h;
    h[0] = (_Float16)T[c2 * 2][n];
    h[1] = (_Float16)T[c2 * 2 + 1][n];
    *(half2v*)&xtb[(size_t)(n0 + n) * 512 + c0 + c2 * 2] = h;
  }
}

// ---------------------------------------------------------------------------
// NT-GEMM: C[m][n] = sum_k A[m][k]*B[n][k].  A fp16 [M,K] lda, B fp16 [N,K] ldb.
// Block 256 thr = 4 waves; block tile 128x128; wave tile 64x64 (4x4 MFMAs).
// TRIPLE-buffered async staging (global_load_lds w=16), prefetch distance 2,
// raw-asm barrier `s_waitcnt vmcnt(4); s_barrier` so the just-issued prefetch
// is NOT drained (only the tile needed now must have landed — in-order vmcnt).
// Bank-conflict-free frag reads via XOR swizzle on the GLOBAL source side:
//   LDS slot (row r, 16B-chunk c') holds global chunk c' ^ ((r>>1)&3).
// TR=false: C[m*ldc + n].  TR=true: C[n*ldc + m]  (transposed output).
// STATS (TR fp16 only): per-m partial softmax stats over this block's 128 n's
// from the ROUNDED fp16 values: pm/ps[b][blockIdx.x][m].
// PROJ3: blocks with m_blk<512 -> TR store into C (ldc); else natural fp16
// store into C2 (ldc2) at row m-512.
// Grid: (N/128, M/128, batches). M,N mult of 128; K mult of 32; ld* mult of 8.
// ---------------------------------------------------------------------------
template <typename OutT, bool TR, bool STATS, bool PROJ3>
__global__ __launch_bounds__(256) void gemm_nt(
    const _Float16* __restrict__ A, const _Float16* __restrict__ B,
    OutT* __restrict__ C, OutT* __restrict__ C2, int K, int lda, int ldb,
    int ldc, int ldc2, long sA, long sB, long sC, float* __restrict__ pm,
    float* __restrict__ ps) {
  A += (size_t)blockIdx.z * sA;
  B += (size_t)blockIdx.z * sB;
  C += (size_t)blockIdx.z * sC;
  if constexpr (PROJ3) C2 += (size_t)blockIdx.z * sC;
  const int m_blk = blockIdx.y * 128, n_blk = blockIdx.x * 128;

  __shared__ _Float16 As[3][4096];  // [buf][128 rows][32 k halves] = 24 KB
  __shared__ _Float16 Bs[3][4096];

  const int t = threadIdx.x;
  const int lane = t & 63, wave = t >> 6;
  const int quad = lane >> 4, l16 = lane & 15;
  const int wm = (wave & 1) * 64, wn = (wave >> 1) * 64;

  // --- staging addressing ---
  const int srow = 16 * wave + (lane >> 2);
  const int schunk = (lane & 3) ^ ((lane >> 3) & 3);  // XOR swizzle
  const _Float16* gA0 = A + (size_t)(m_blk + srow) * lda + schunk * 8;
  const _Float16* gA1 = gA0 + (size_t)64 * lda;
  const _Float16* gB0 = B + (size_t)(n_blk + srow) * ldb + schunk * 8;
  const _Float16* gB1 = gB0 + (size_t)64 * ldb;
  const int lofs = wave * 512 + lane * 8;  // halves within one buffer

  // --- frag-read addressing (undo swizzle: chunk = quad ^ ((l16>>1)&3)) ---
  const int rchunk = (quad ^ ((l16 >> 1) & 3)) * 8;

  f32x4 acc[4][4] = {};

  // prologue: stage tiles 0 and 1
  ASYNC_CP16(gA0, &As[0][lofs]);
  ASYNC_CP16(gA1, &As[0][lofs + 2048]);
  ASYNC_CP16(gB0, &Bs[0][lofs]);
  ASYNC_CP16(gB1, &Bs[0][lofs + 2048]);
  if (32 < K) {
    ASYNC_CP16(gA0 + 32, &As[1][lofs]);
    ASYNC_CP16(gA1 + 32, &As[1][lofs + 2048]);
    ASYNC_CP16(gB0 + 32, &Bs[1][lofs]);
    ASYNC_CP16(gB1 + 32, &Bs[1][lofs + 2048]);
  }

  int ib = 0;
  for (int k0 = 0; k0 < K; k0 += 32) {
    // barrier: tile k0 must have landed; tile k0+32's 4 loads may remain
    // outstanding (in-order vmcnt retirement). Also orders buffer reuse.
    if (k0 + 32 < K) {
      asm volatile("s_waitcnt vmcnt(4)\n\ts_barrier" ::: "memory");
    } else {
      asm volatile("s_waitcnt vmcnt(0)\n\ts_barrier" ::: "memory");
    }
    if (k0 + 64 < K) {  // prefetch tile k0+64 into buffer (ib+2)%3
      int nb = ib + 2;
      if (nb >= 3) nb -= 3;
      ASYNC_CP16(gA0 + k0 + 64, &As[nb][lofs]);
      ASYNC_CP16(gA1 + k0 + 64, &As[nb][lofs + 2048]);
      ASYNC_CP16(gB0 + k0 + 64, &Bs[nb][lofs]);
      ASYNC_CP16(gB1 + k0 + 64, &Bs[nb][lofs + 2048]);
    }
    half8 af[4], bf[4];
#pragma unroll
    for (int i = 0; i < 4; i++) {
      af[i] = *(const half8*)&As[ib][(wm + i * 16 + l16) * 32 + rchunk];
      bf[i] = *(const half8*)&Bs[ib][(wn + i * 16 + l16) * 32 + rchunk];
    }
#pragma unroll
    for (int i = 0; i < 4; i++)
#pragma unroll
      for (int j = 0; j < 4; j++)
        acc[i][j] =
            __builtin_amdgcn_mfma_f32_16x16x32_f16(af[i], bf[j], acc[i][j], 0, 0, 0);
    ib++;
    if (ib == 3) ib = 0;
  }

  // epilogue: D element (row = quad*4 + reg, col = l16) within each 16x16 tile
#pragma unroll
  for (int i = 0; i < 4; i++) {
    const int m0 = m_blk + wm + i * 16 + quad * 4;
#pragma unroll
    for (int j = 0; j < 4; j++) {
      const int n0 = n_blk + wn + j * 16 + l16;
      if constexpr (PROJ3) {
        if (m_blk < 512) {  // q|k rows: transposed store into qkT
          half4v h;
#pragma unroll
          for (int r = 0; r < 4; r++) h[r] = (_Float16)acc[i][j][r];
          *(half4v*)&C[(size_t)n0 * ldc + m0] = h;
        } else {  // v rows: natural store v[(m-512)][n]
#pragma unroll
          for (int r = 0; r < 4; r++)
            C2[(size_t)(m0 - 512 + r) * ldc2 + n0] = (OutT)acc[i][j][r];
        }
      } else if constexpr (TR) {
        if constexpr (sizeof(OutT) == 4) {
          *(f32x4*)&C[(size_t)n0 * ldc + m0] = acc[i][j];
        } else {
          half4v h;
#pragma unroll
          for (int r = 0; r < 4; r++) h[r] = (_Float16)acc[i][j][r];
          if constexpr (STATS) {  // keep rounded values for consistent stats
#pragma unroll
            for (int r = 0; r < 4; r++) acc[i][j][r] = (float)h[r];
          }
          *(half4v*)&C[(size_t)n0 * ldc + m0] = h;
        }
      } else {
#pragma unroll
        for (int r = 0; r < 4; r++)
          C[(size_t)(m0 + r) * ldc + n0] = (OutT)acc[i][j][r];
      }
    }
  }

  // fused partial softmax stats (per gemm-m, over this block's 128 n's)
  if constexpr (STATS) {
    __shared__ float sred[2][128][2];  // [n-half][m_local][max|sum]
    const int wng = wave >> 1;         // which 64-n half this wave covers
    float bmax[4][4], bsum[4][4];
#pragma unroll
    for (int i = 0; i < 4; i++) {
#pragma unroll
      for (int r = 0; r < 4; r++) {
        float mx = acc[i][0][r];
#pragma unroll
        for (int j = 1; j < 4; j++) mx = fmaxf(mx, acc[i][j][r]);
#pragma unroll
        for (int d = 1; d < 16; d <<= 1)
          mx = fmaxf(mx, __shfl_xor(mx, d, 64));
        float es = 0.f;
#pragma unroll
        for (int j = 0; j < 4; j++) es += __expf(acc[i][j][r] - mx);
#pragma unroll
        for (int d = 1; d < 16; d <<= 1) es += __shfl_xor(es, d, 64);
        bmax[i][r] = mx;
        bsum[i][r] = es;
      }
    }
    if (l16 == 0) {
#pragma unroll
      for (int i = 0; i < 4; i++)
#pragma unroll
        for (int r = 0; r < 4; r++) {
          int ml = wm + i * 16 + quad * 4 + r;
          sred[wng][ml][0] = bmax[i][r];
          sred[wng][ml][1] = bsum[i][r];
        }
    }
    __syncthreads();
    if (t < 128) {
      float m0 = sred[0][t][0], s0 = sred[0][t][1];
      float m1 = sred[1][t][0], s1 = sred[1][t][1];
      float M = fmaxf(m0, m1);
      float S = s0 * __expf(m0 - M) + s1 * __expf(m1 - M);
      size_t o = ((size_t)blockIdx.z * 16 + blockIdx.x) * 2048 + m_blk + t;
      pm[o] = M;
      ps[o] = S;
    }
  }
}

// ---------------------------------------------------------------------------
// Column-stats stage 2: merge 16 partials -> shift[col] = max + ln(sum), so
// attn weight = exp(x - shift).  Grid (nb*2048/256).
// ---------------------------------------------------------------------------
__global__ __launch_bounds__(256) void colstats2(const float* __restrict__ pm,
                                                 const float* __restrict__ ps,
                                                 float* __restrict__ shift) {
  const int idx = blockIdx.x * 256 + threadIdx.x;  // b*2048 + col
  const int b = idx >> 11, col = idx & 2047;
  const float* pmb = pm + (size_t)b * 16 * 2048 + col;
  const float* psb = ps + (size_t)b * 16 * 2048 + col;
  float m = -3.0e38f;
#pragma unroll
  for (int i = 0; i < 16; i++) m = fmaxf(m, pmb[(size_t)i * 2048]);
  float s = 0.f;
#pragma unroll
  for (int i = 0; i < 16; i++)
    s += psb[(size_t)i * 2048] * __expf(pmb[(size_t)i * 2048] - m);
  shift[idx] = m + __logf(s);
}

// ---------------------------------------------------------------------------
// In-place: simH[m][k] = fp16( exp(simH[m][k] - shift[k]) ).  Per-thread half8.
// Grid (2048, nb).
// ---------------------------------------------------------------------------
__global__ __launch_bounds__(256) void attnscale(_Float16* __restrict__ simH,
                                                 const float* __restrict__ shift) {
  const size_t b = blockIdx.y;
  const size_t g = (size_t)blockIdx.x * 256 + threadIdx.x;  // half8 group
  const int col = (int)(g & 255) * 8;
  _Float16* p = simH + b * (2048ull * 2048) + g * 8;
  half8 h = *(const half8*)p;
  f32x4 s0 = *(const f32x4*)(shift + b * 2048 + col);
  f32x4 s1 = *(const f32x4*)(shift + b * 2048 + col + 4);
  half8 o;
#pragma unroll
  for (int i = 0; i < 4; i++) {
    o[i] = (_Float16)__expf((float)h[i] - s0[i]);
    o[i + 4] = (_Float16)__expf((float)h[i + 4] - s1[i]);
  }
  *(half8*)p = o;
}

// ---------------------------------------------------------------------------
extern "C" void kernel_launch(void* const* d_in, const int* in_sizes, int n_in,
                              void* d_out, int out_size, void* d_ws,
                              size_t ws_size, hipStream_t stream) {
  const float* x = (const float*)d_in[0];
  const float* Wq = (const float*)d_in[1];
  const float* Wk = (const float*)d_in[2];
  const float* Wv = (const float*)d_in[3];
  float* out = (float*)d_out;

  char* p = (char*)d_ws;
  auto alloc = [&](size_t bytes) -> char* {
    char* r = p;
    p += (bytes + 255) & ~(size_t)255;
    return r;
  };
  const size_t NB = 8, N = 2048, CIN = 512, CO = 512;
  _Float16* Wb = (_Float16*)alloc(1024 * 512 * sizeof(_Float16));
  _Float16* xT = (_Float16*)alloc(NB * N * CIN * sizeof(_Float16));
  _Float16* qkT = (_Float16*)alloc(NB * N * 512 * sizeof(_Float16));  // [n][q|k]
  _Float16* v = (_Float16*)alloc(NB * CO * N * sizeof(_Float16));     // [c][n]
  size_t base_used = (size_t)(p - (char*)d_ws);

  // per-batch bytes for the sim chain: fp16 logits + partials + shift + slack
  const size_t per_b =
      (size_t)N * N * 2 + 2 * 16 * N * 4 + N * 4 + 8192;
  int cb = 8;
  while (cb > 1 && base_used + (size_t)cb * per_b > ws_size) cb >>= 1;
  _Float16* simH = (_Float16*)alloc((size_t)cb * N * N * 2);
  float* pm = (float*)alloc((size_t)cb * 16 * N * 4);
  float* ps = (float*)alloc((size_t)cb * 16 * N * 4);
  float* shift = (float*)alloc((size_t)cb * N * 4);

  // 1) weight convert + x transpose-convert
  conv_w<<<dim3(1024 * 512 / 256), 256, 0, stream>>>(Wq, Wk, Wv, Wb);
  conv_xT<<<dim3(64, 16, 8), 256, 0, stream>>>(x, xT);

  // 2) merged projections (q,k,v in one pass over xT):
  //    rows<512 -> qkT[n][o] transposed; rows>=512 -> v[c][n] natural
  gemm_nt<_Float16, true, false, true><<<dim3(16, 8, 8), 256, 0, stream>>>(
      Wb, xT, qkT, v, 512, 512, 512, 512, 2048, 0, (long)(N * CIN),
      (long)(N * 512), nullptr, nullptr);

  // 3) per-chunk: simH = fp16((kT . qT^T)^T) with fused softmax partials;
  //    merge stats; in-place exp; out = attn . v^T
  for (int b0 = 0; b0 < 8; b0 += cb) {
    const _Float16* kT = qkT + (size_t)b0 * N * 512 + 256;  // [i][c], lda 512
    const _Float16* qT = qkT + (size_t)b0 * N * 512;        // [j][c], ldb 512
    gemm_nt<_Float16, true, true, false><<<dim3(16, 16, cb), 256, 0, stream>>>(
        kT, qT, simH, nullptr, 256, 512, 512, 2048, 0, (long)(N * 512),
        (long)(N * 512), (long)(N * N), pm, ps);
    colstats2<<<dim3(cb * 8), 256, 0, stream>>>(pm, ps, shift);
    attnscale<<<dim3(2048, cb), 256, 0, stream>>>(simH, shift);
    gemm_nt<float, false, false, false><<<dim3(4, 16, cb), 256, 0, stream>>>(
        simH, v + (size_t)b0 * CO * N, out + (size_t)b0 * N * CO, nullptr,
        2048, 2048, 2048, 512, 0, (long)(N * N), (long)(CO * N),
        (long)(N * CO), nullptr, nullptr);
  }
}

// Round 7
// 229.255 us; speedup vs baseline: 2.2038x; 1.0436x over previous
//
#include <hip/hip_runtime.h>

typedef _Float16 half8 __attribute__((ext_vector_type(8)));
typedef _Float16 half4v __attribute__((ext_vector_type(4)));
typedef _Float16 half2v __attribute__((ext_vector_type(2)));
typedef float f32x4 __attribute__((ext_vector_type(4)));

// async 16B global->LDS copy (HW: LDS dest = wave-uniform base + lane*16)
#define ASYNC_CP16(gp, lp)                                       \
  __builtin_amdgcn_global_load_lds(                              \
      (const __attribute__((address_space(1))) void*)(gp),       \
      (__attribute__((address_space(3))) void*)(lp), 16, 0, 0)

// ---------------------------------------------------------------------------
// Convert Wq||Wk||Wv (fp32 [O,512] each) -> Wb fp16 [1024][512] (c-inner)
// ---------------------------------------------------------------------------
__global__ __launch_bounds__(256) void conv_w(const float* __restrict__ Wq,
                                              const float* __restrict__ Wk,
                                              const float* __restrict__ Wv,
                                              _Float16* __restrict__ Wb) {
  int idx = blockIdx.x * 256 + threadIdx.x;  // 0 .. 1024*512
  int row = idx >> 9;
  float v;
  if (row < 256)      v = Wq[idx];
  else if (row < 512) v = Wk[idx - 256 * 512];
  else                v = Wv[idx - 512 * 512];
  Wb[idx] = (_Float16)v;
}

// ---------------------------------------------------------------------------
// x fp32 [B][512][2048] -> xT fp16 [B][2048][512]   (LDS-tiled transpose)
// ---------------------------------------------------------------------------
__global__ __launch_bounds__(256) void conv_xT(const float* __restrict__ x,
                                               _Float16* __restrict__ xT) {
  __shared__ float T[32][33];
  const int b = blockIdx.z;
  const int n0 = blockIdx.x * 32, c0 = blockIdx.y * 32;
  const int t = threadIdx.x;
  const float* xb = x + (size_t)b * 512 * 2048;
  const int n2 = t & 15, cr = t >> 4;  // load: 16 float2-cols x 16 c-rows
#pragma unroll
  for (int r = 0; r < 2; r++) {
    int c = cr + r * 16;
    float2 v = *(const float2*)&xb[(size_t)(c0 + c) * 2048 + n0 + n2 * 2];
    T[c][n2 * 2] = v.x;
    T[c][n2 * 2 + 1] = v.y;
  }
  __syncthreads();
  _Float16* xtb = xT + (size_t)b * 2048 * 512;
  const int c2 = t & 15, nr = t >> 4;  // store: 16 half2-cols x 16 n-rows
#pragma unroll
  for (int r = 0; r < 2; r++) {
    int n = nr + r * 16;
    half2v h;
    h[0] = (_Float16)T[c2 * 2][n];
    h[1] = (_Float16)T[c2 * 2 + 1][n];
    *(half2v*)&xtb[(size_t)(n0 + n) * 512 + c0 + c2 * 2] = h;
  }
}

// ---------------------------------------------------------------------------
// NT-GEMM: C[m][n] = sum_k A[m][k]*B[n][k].  A fp16 [M,K] lda, B fp16 [N,K] ldb.
// Block 256 thr = 4 waves; block tile 128x128; wave tile 64x64 (4x4 MFMAs).
// BUFS-buffered async staging (global_load_lds w=16), prefetch dist BUFS-1,
// raw-asm barrier `s_waitcnt vmcnt(N); s_barrier` (N=4 for BUFS=3 mid-loop:
// only the newest tile's 4 loads may stay in flight; in-order vmcnt retire).
// Bank-conflict-free frag reads via XOR swizzle on the GLOBAL source side:
//   LDS slot (row r, 16B-chunk c') holds global chunk c' ^ ((r>>1)&3).
// MODE 0: natural store C[m*ldc+n].
// MODE 1 (PROJ3): m_blk<512 -> transposed fp16 store into C (qkT); else
//   natural fp16 store into C2 (v) at row m-512.
// MODE 2 (SIM): natural fp16 store (rounded), plus per-column-n partial
//   softmax stats over this block's 128 m's -> pm/ps[b][blockIdx.y][n].
//   (stats reduce over quad lanes: 2 shfl_xor + LDS wave-pair merge)
// Grid: (N/128, M/128, batches). M,N mult of 128; K mult of 32; ld* mult of 8.
// ---------------------------------------------------------------------------
template <typename OutT, int BUFS, int MODE>
__global__ __launch_bounds__(256) void gemm_nt(
    const _Float16* __restrict__ A, const _Float16* __restrict__ B,
    OutT* __restrict__ C, OutT* __restrict__ C2, int K, int lda, int ldb,
    int ldc, int ldc2, long sA, long sB, long sC, float* __restrict__ pm,
    float* __restrict__ ps) {
  A += (size_t)blockIdx.z * sA;
  B += (size_t)blockIdx.z * sB;
  C += (size_t)blockIdx.z * sC;
  if constexpr (MODE == 1) C2 += (size_t)blockIdx.z * sC;
  const int m_blk = blockIdx.y * 128, n_blk = blockIdx.x * 128;

  __shared__ _Float16 As[BUFS][4096];  // [buf][128 rows][32 k halves]
  __shared__ _Float16 Bs[BUFS][4096];

  const int t = threadIdx.x;
  const int lane = t & 63, wave = t >> 6;
  const int quad = lane >> 4, l16 = lane & 15;
  const int wm = (wave & 1) * 64, wn = (wave >> 1) * 64;

  // --- staging addressing ---
  const int srow = 16 * wave + (lane >> 2);
  const int schunk = (lane & 3) ^ ((lane >> 3) & 3);  // XOR swizzle
  const _Float16* gA0 = A + (size_t)(m_blk + srow) * lda + schunk * 8;
  const _Float16* gA1 = gA0 + (size_t)64 * lda;
  const _Float16* gB0 = B + (size_t)(n_blk + srow) * ldb + schunk * 8;
  const _Float16* gB1 = gB0 + (size_t)64 * ldb;
  const int lofs = wave * 512 + lane * 8;  // halves within one buffer

  // --- frag-read addressing (undo swizzle: chunk = quad ^ ((l16>>1)&3)) ---
  const int rchunk = (quad ^ ((l16 >> 1) & 3)) * 8;

  f32x4 acc[4][4] = {};

  // prologue: stage tiles 0..BUFS-2
#pragma unroll
  for (int pb = 0; pb < BUFS - 1; pb++) {
    if (pb * 32 < K) {
      ASYNC_CP16(gA0 + pb * 32, &As[pb][lofs]);
      ASYNC_CP16(gA1 + pb * 32, &As[pb][lofs + 2048]);
      ASYNC_CP16(gB0 + pb * 32, &Bs[pb][lofs]);
      ASYNC_CP16(gB1 + pb * 32, &Bs[pb][lofs + 2048]);
    }
  }

  int ib = 0;
  for (int k0 = 0; k0 < K; k0 += 32) {
    // barrier: tile k0 must have landed in ALL waves; with BUFS=3 only the
    // newest prefetched tile (4 loads) may remain outstanding.
    if constexpr (BUFS == 3) {
      if (k0 + 32 < K)
        asm volatile("s_waitcnt vmcnt(4)\n\ts_barrier" ::: "memory");
      else
        asm volatile("s_waitcnt vmcnt(0)\n\ts_barrier" ::: "memory");
    } else {
      asm volatile("s_waitcnt vmcnt(0)\n\ts_barrier" ::: "memory");
    }
    if (k0 + (BUFS - 1) * 32 < K) {  // prefetch into buffer (ib+BUFS-1)%BUFS
      int nb = ib + BUFS - 1;
      if (nb >= BUFS) nb -= BUFS;
      const int ko = k0 + (BUFS - 1) * 32;
      ASYNC_CP16(gA0 + ko, &As[nb][lofs]);
      ASYNC_CP16(gA1 + ko, &As[nb][lofs + 2048]);
      ASYNC_CP16(gB0 + ko, &Bs[nb][lofs]);
      ASYNC_CP16(gB1 + ko, &Bs[nb][lofs + 2048]);
    }
    half8 af[4], bf[4];
#pragma unroll
    for (int i = 0; i < 4; i++) {
      af[i] = *(const half8*)&As[ib][(wm + i * 16 + l16) * 32 + rchunk];
      bf[i] = *(const half8*)&Bs[ib][(wn + i * 16 + l16) * 32 + rchunk];
    }
#pragma unroll
    for (int i = 0; i < 4; i++)
#pragma unroll
      for (int j = 0; j < 4; j++)
        acc[i][j] =
            __builtin_amdgcn_mfma_f32_16x16x32_f16(af[i], bf[j], acc[i][j], 0, 0, 0);
    ib++;
    if (ib == BUFS) ib = 0;
  }

  // epilogue: D element (row = quad*4 + reg, col = l16) within each 16x16 tile
#pragma unroll
  for (int i = 0; i < 4; i++) {
    const int m0 = m_blk + wm + i * 16 + quad * 4;
#pragma unroll
    for (int j = 0; j < 4; j++) {
      const int n0 = n_blk + wn + j * 16 + l16;
      if constexpr (MODE == 1) {
        if (m_blk < 512) {  // q|k rows: transposed store into qkT
          half4v h;
#pragma unroll
          for (int r = 0; r < 4; r++) h[r] = (_Float16)acc[i][j][r];
          *(half4v*)&C[(size_t)n0 * ldc + m0] = h;
        } else {  // v rows: natural store v[(m-512)][n]
#pragma unroll
          for (int r = 0; r < 4; r++)
            C2[(size_t)(m0 - 512 + r) * ldc2 + n0] = (OutT)acc[i][j][r];
        }
      } else if constexpr (MODE == 2) {
#pragma unroll
        for (int r = 0; r < 4; r++) {
          _Float16 h = (_Float16)acc[i][j][r];
          C[(size_t)(m0 + r) * ldc + n0] = h;
          acc[i][j][r] = (float)h;  // rounded value feeds the stats
        }
      } else {
#pragma unroll
        for (int r = 0; r < 4; r++)
          C[(size_t)(m0 + r) * ldc + n0] = (OutT)acc[i][j][r];
      }
    }
  }

  // fused partial softmax stats: per column n, over this block's 128 m's.
  // Thread's 16 (i,r) values share column n0(j); quad lanes (bits 4,5) hold
  // the other m's of this wave -> 2 shfl_xor; wave-pair merged via LDS.
  if constexpr (MODE == 2) {
    __shared__ float sred[128][2][2];  // [n_local][m-wave-group][max|sum]
    float pM[4], pS[4];
#pragma unroll
    for (int j = 0; j < 4; j++) {
      float mx = acc[0][j][0];
#pragma unroll
      for (int i = 0; i < 4; i++)
#pragma unroll
        for (int r = 0; r < 4; r++) mx = fmaxf(mx, acc[i][j][r]);
      mx = fmaxf(mx, __shfl_xor(mx, 16, 64));
      mx = fmaxf(mx, __shfl_xor(mx, 32, 64));
      float es = 0.f;
#pragma unroll
      for (int i = 0; i < 4; i++)
#pragma unroll
        for (int r = 0; r < 4; r++) es += __expf(acc[i][j][r] - mx);
      es += __shfl_xor(es, 16, 64);
      es += __shfl_xor(es, 32, 64);
      pM[j] = mx;
      pS[j] = es;
    }
    if (quad == 0) {
#pragma unroll
      for (int j = 0; j < 4; j++) {
        sred[wn + j * 16 + l16][wave & 1][0] = pM[j];
        sred[wn + j * 16 + l16][wave & 1][1] = pS[j];
      }
    }
    __syncthreads();
    if (t < 128) {
      float m0 = sred[t][0][0], s0 = sred[t][0][1];
      float m1 = sred[t][1][0], s1 = sred[t][1][1];
      float M = fmaxf(m0, m1);
      float S = s0 * __expf(m0 - M) + s1 * __expf(m1 - M);
      size_t o = ((size_t)blockIdx.z * 16 + blockIdx.y) * 2048 + n_blk + t;
      pm[o] = M;
      ps[o] = S;
    }
  }
}

// ---------------------------------------------------------------------------
// Column-stats stage 2: merge 16 partials -> shift[col] = max + ln(sum), so
// attn weight = exp(x - shift).  Grid (nb*2048/256).
// ---------------------------------------------------------------------------
__global__ __launch_bounds__(256) void colstats2(const float* __restrict__ pm,
                                                 const float* __restrict__ ps,
                                                 float* __restrict__ shift) {
  const int idx = blockIdx.x * 256 + threadIdx.x;  // b*2048 + col
  const int b = idx >> 11, col = idx & 2047;
  const float* pmb = pm + (size_t)b * 16 * 2048 + col;
  const float* psb = ps + (size_t)b * 16 * 2048 + col;
  float m = -3.0e38f;
#pragma unroll
  for (int i = 0; i < 16; i++) m = fmaxf(m, pmb[(size_t)i * 2048]);
  float s = 0.f;
#pragma unroll
  for (int i = 0; i < 16; i++)
    s += psb[(size_t)i * 2048] * __expf(pmb[(size_t)i * 2048] - m);
  shift[idx] = m + __logf(s);
}

// ---------------------------------------------------------------------------
// In-place: simH[m][k] = fp16( exp(simH[m][k] - shift[k]) ).  Per-thread half8.
// Grid (2048, nb).
// ---------------------------------------------------------------------------
__global__ __launch_bounds__(256) void attnscale(_Float16* __restrict__ simH,
                                                 const float* __restrict__ shift) {
  const size_t b = blockIdx.y;
  const size_t g = (size_t)blockIdx.x * 256 + threadIdx.x;  // half8 group
  const int col = (int)(g & 255) * 8;
  _Float16* p = simH + b * (2048ull * 2048) + g * 8;
  half8 h = *(const half8*)p;
  f32x4 s0 = *(const f32x4*)(shift + b * 2048 + col);
  f32x4 s1 = *(const f32x4*)(shift + b * 2048 + col + 4);
  half8 o;
#pragma unroll
  for (int i = 0; i < 4; i++) {
    o[i] = (_Float16)__expf((float)h[i] - s0[i]);
    o[i + 4] = (_Float16)__expf((float)h[i + 4] - s1[i]);
  }
  *(half8*)p = o;
}

// ---------------------------------------------------------------------------
extern "C" void kernel_launch(void* const* d_in, const int* in_sizes, int n_in,
                              void* d_out, int out_size, void* d_ws,
                              size_t ws_size, hipStream_t stream) {
  const float* x = (const float*)d_in[0];
  const float* Wq = (const float*)d_in[1];
  const float* Wk = (const float*)d_in[2];
  const float* Wv = (const float*)d_in[3];
  float* out = (float*)d_out;

  char* p = (char*)d_ws;
  auto alloc = [&](size_t bytes) -> char* {
    char* r = p;
    p += (bytes + 255) & ~(size_t)255;
    return r;
  };
  const size_t NB = 8, N = 2048, CIN = 512, CO = 512;
  _Float16* Wb = (_Float16*)alloc(1024 * 512 * sizeof(_Float16));
  _Float16* xT = (_Float16*)alloc(NB * N * CIN * sizeof(_Float16));
  _Float16* qkT = (_Float16*)alloc(NB * N * 512 * sizeof(_Float16));  // [n][q|k]
  _Float16* v = (_Float16*)alloc(NB * CO * N * sizeof(_Float16));     // [c][n]
  size_t base_used = (size_t)(p - (char*)d_ws);

  // per-batch bytes for the sim chain: fp16 logits + partials + shift + slack
  const size_t per_b =
      (size_t)N * N * 2 + 2 * 16 * N * 4 + N * 4 + 8192;
  int cb = 8;
  while (cb > 1 && base_used + (size_t)cb * per_b > ws_size) cb >>= 1;
  _Float16* simH = (_Float16*)alloc((size_t)cb * N * N * 2);
  float* pm = (float*)alloc((size_t)cb * 16 * N * 4);
  float* ps = (float*)alloc((size_t)cb * 16 * N * 4);
  float* shift = (float*)alloc((size_t)cb * N * 4);

  // 1) weight convert + x transpose-convert
  conv_w<<<dim3(1024 * 512 / 256), 256, 0, stream>>>(Wq, Wk, Wv, Wb);
  conv_xT<<<dim3(64, 16, 8), 256, 0, stream>>>(x, xT);

  // 2) merged projections (q,k,v in one pass over xT):
  //    rows<512 -> qkT[n][o] transposed; rows>=512 -> v[c][n] natural
  gemm_nt<_Float16, 3, 1><<<dim3(16, 8, 8), 256, 0, stream>>>(
      Wb, xT, qkT, v, 512, 512, 512, 512, 2048, 0, (long)(N * CIN),
      (long)(N * 512), nullptr, nullptr);

  // 3) per-chunk: simH[m][k] = fp16(qT . kT^T) natural (A=qT!), with fused
  //    softmax partials over m; merge stats; in-place exp; out = attn . v^T
  for (int b0 = 0; b0 < 8; b0 += cb) {
    const _Float16* qT = qkT + (size_t)b0 * N * 512;        // [m][c], lda 512
    const _Float16* kT = qkT + (size_t)b0 * N * 512 + 256;  // [k][c], ldb 512
    gemm_nt<_Float16, 2, 2><<<dim3(16, 16, cb), 256, 0, stream>>>(
        qT, kT, simH, nullptr, 256, 512, 512, 2048, 0, (long)(N * 512),
        (long)(N * 512), (long)(N * N), pm, ps);
    colstats2<<<dim3(cb * 8), 256, 0, stream>>>(pm, ps, shift);
    attnscale<<<dim3(2048, cb), 256, 0, stream>>>(simH, shift);
    gemm_nt<float, 3, 0><<<dim3(4, 16, cb), 256, 0, stream>>>(
        simH, v + (size_t)b0 * CO * N, out + (size_t)b0 * N * CO, nullptr,
        2048, 2048, 2048, 512, 0, (long)(N * N), (long)(CO * N),
        (long)(N * CO), nullptr, nullptr);
  }
}

// Round 8
// 225.455 us; speedup vs baseline: 2.2409x; 1.0169x over previous
//
#include <hip/hip_runtime.h>

typedef _Float16 half8 __attribute__((ext_vector_type(8)));
typedef _Float16 half4v __attribute__((ext_vector_type(4)));
typedef _Float16 half2v __attribute__((ext_vector_type(2)));
typedef float f32x4 __attribute__((ext_vector_type(4)));

// async 16B global->LDS copy (HW: LDS dest = wave-uniform base + lane*16)
#define ASYNC_CP16(gp, lp)                                       \
  __builtin_amdgcn_global_load_lds(                              \
      (const __attribute__((address_space(1))) void*)(gp),       \
      (__attribute__((address_space(3))) void*)(lp), 16, 0, 0)

// ---------------------------------------------------------------------------
// Convert Wq||Wk||Wv (fp32 [O,512] each) -> Wb fp16 [1024][512] (c-inner)
// ---------------------------------------------------------------------------
__global__ __launch_bounds__(256) void conv_w(const float* __restrict__ Wq,
                                              const float* __restrict__ Wk,
                                              const float* __restrict__ Wv,
                                              _Float16* __restrict__ Wb) {
  int idx = blockIdx.x * 256 + threadIdx.x;  // 0 .. 1024*512
  int row = idx >> 9;
  float v;
  if (row < 256)      v = Wq[idx];
  else if (row < 512) v = Wk[idx - 256 * 512];
  else                v = Wv[idx - 512 * 512];
  Wb[idx] = (_Float16)v;
}

// ---------------------------------------------------------------------------
// x fp32 [B][512][2048] -> xT fp16 [B][2048][512]   (LDS-tiled transpose)
// ---------------------------------------------------------------------------
__global__ __launch_bounds__(256) void conv_xT(const float* __restrict__ x,
                                               _Float16* __restrict__ xT) {
  __shared__ float T[32][33];
  const int b = blockIdx.z;
  const int n0 = blockIdx.x * 32, c0 = blockIdx.y * 32;
  const int t = threadIdx.x;
  const float* xb = x + (size_t)b * 512 * 2048;
  const int n2 = t & 15, cr = t >> 4;  // load: 16 float2-cols x 16 c-rows
#pragma unroll
  for (int r = 0; r < 2; r++) {
    int c = cr + r * 16;
    float2 v = *(const float2*)&xb[(size_t)(c0 + c) * 2048 + n0 + n2 * 2];
    T[c][n2 * 2] = v.x;
    T[c][n2 * 2 + 1] = v.y;
  }
  __syncthreads();
  _Float16* xtb = xT + (size_t)b * 2048 * 512;
  const int c2 = t & 15, nr = t >> 4;  // store: 16 half2-cols x 16 n-rows
#pragma unroll
  for (int r = 0; r < 2; r++) {
    int n = nr + r * 16;
    half2v h;
    h[0] = (_Float16)T[c2 * 2][n];
    h[1] = (_Float16)T[c2 * 2 + 1][n];
    *(half2v*)&xtb[(size_t)(n0 + n) * 512 + c0 + c2 * 2] = h;
  }
}

// ---------------------------------------------------------------------------
// NT-GEMM (proj + sim): C[m][n] = sum_k A[m][k]*B[n][k], fp16 in.
// Block 256 thr = 4 waves; block tile 128x128; wave tile 64x64 (4x4 MFMAs).
// BUFS-buffered async staging (global_load_lds w=16), prefetch dist BUFS-1,
// raw-asm barrier (vmcnt(4) mid-loop for BUFS=3; in-order vmcnt retire).
// XOR swizzle on the GLOBAL source side keeps frag ds_read_b128 conflict-free:
//   LDS slot (row r, 16B-chunk c') holds global chunk c' ^ ((r>>1)&3).
// MODE 1 (PROJ3): m_blk<512 -> transposed fp16 store into C (qkT); else
//   natural fp16 store into C2 (v) at row m-512.
// MODE 2 (SIM): natural fp16 store (rounded), plus per-column-n partial
//   softmax stats over this block's 128 m's -> pm/ps[b][blockIdx.y][n].
// ---------------------------------------------------------------------------
template <typename OutT, int BUFS, int MODE>
__global__ __launch_bounds__(256) void gemm_nt(
    const _Float16* __restrict__ A, const _Float16* __restrict__ B,
    OutT* __restrict__ C, OutT* __restrict__ C2, int K, int lda, int ldb,
    int ldc, int ldc2, long sA, long sB, long sC, float* __restrict__ pm,
    float* __restrict__ ps) {
  A += (size_t)blockIdx.z * sA;
  B += (size_t)blockIdx.z * sB;
  C += (size_t)blockIdx.z * sC;
  if constexpr (MODE == 1) C2 += (size_t)blockIdx.z * sC;
  const int m_blk = blockIdx.y * 128, n_blk = blockIdx.x * 128;

  __shared__ _Float16 As[BUFS][4096];  // [buf][128 rows][32 k halves]
  __shared__ _Float16 Bs[BUFS][4096];

  const int t = threadIdx.x;
  const int lane = t & 63, wave = t >> 6;
  const int quad = lane >> 4, l16 = lane & 15;
  const int wm = (wave & 1) * 64, wn = (wave >> 1) * 64;

  const int srow = 16 * wave + (lane >> 2);
  const int schunk = (lane & 3) ^ ((lane >> 3) & 3);  // XOR swizzle
  const _Float16* gA0 = A + (size_t)(m_blk + srow) * lda + schunk * 8;
  const _Float16* gA1 = gA0 + (size_t)64 * lda;
  const _Float16* gB0 = B + (size_t)(n_blk + srow) * ldb + schunk * 8;
  const _Float16* gB1 = gB0 + (size_t)64 * ldb;
  const int lofs = wave * 512 + lane * 8;  // halves within one buffer

  const int rchunk = (quad ^ ((l16 >> 1) & 3)) * 8;

  f32x4 acc[4][4] = {};

#pragma unroll
  for (int pb = 0; pb < BUFS - 1; pb++) {
    if (pb * 32 < K) {
      ASYNC_CP16(gA0 + pb * 32, &As[pb][lofs]);
      ASYNC_CP16(gA1 + pb * 32, &As[pb][lofs + 2048]);
      ASYNC_CP16(gB0 + pb * 32, &Bs[pb][lofs]);
      ASYNC_CP16(gB1 + pb * 32, &Bs[pb][lofs + 2048]);
    }
  }

  int ib = 0;
  for (int k0 = 0; k0 < K; k0 += 32) {
    if constexpr (BUFS == 3) {
      if (k0 + 32 < K)
        asm volatile("s_waitcnt vmcnt(4)\n\ts_barrier" ::: "memory");
      else
        asm volatile("s_waitcnt vmcnt(0)\n\ts_barrier" ::: "memory");
    } else {
      asm volatile("s_waitcnt vmcnt(0)\n\ts_barrier" ::: "memory");
    }
    if (k0 + (BUFS - 1) * 32 < K) {
      int nb = ib + BUFS - 1;
      if (nb >= BUFS) nb -= BUFS;
      const int ko = k0 + (BUFS - 1) * 32;
      ASYNC_CP16(gA0 + ko, &As[nb][lofs]);
      ASYNC_CP16(gA1 + ko, &As[nb][lofs + 2048]);
      ASYNC_CP16(gB0 + ko, &Bs[nb][lofs]);
      ASYNC_CP16(gB1 + ko, &Bs[nb][lofs + 2048]);
    }
    half8 af[4], bf[4];
#pragma unroll
    for (int i = 0; i < 4; i++) {
      af[i] = *(const half8*)&As[ib][(wm + i * 16 + l16) * 32 + rchunk];
      bf[i] = *(const half8*)&Bs[ib][(wn + i * 16 + l16) * 32 + rchunk];
    }
#pragma unroll
    for (int i = 0; i < 4; i++)
#pragma unroll
      for (int j = 0; j < 4; j++)
        acc[i][j] =
            __builtin_amdgcn_mfma_f32_16x16x32_f16(af[i], bf[j], acc[i][j], 0, 0, 0);
    ib++;
    if (ib == BUFS) ib = 0;
  }

  // epilogue: D element (row = quad*4 + reg, col = l16) within each 16x16 tile
#pragma unroll
  for (int i = 0; i < 4; i++) {
    const int m0 = m_blk + wm + i * 16 + quad * 4;
#pragma unroll
    for (int j = 0; j < 4; j++) {
      const int n0 = n_blk + wn + j * 16 + l16;
      if constexpr (MODE == 1) {
        if (m_blk < 512) {  // q|k rows: transposed store into qkT
          half4v h;
#pragma unroll
          for (int r = 0; r < 4; r++) h[r] = (_Float16)acc[i][j][r];
          *(half4v*)&C[(size_t)n0 * ldc + m0] = h;
        } else {  // v rows: natural store v[(m-512)][n]
#pragma unroll
          for (int r = 0; r < 4; r++)
            C2[(size_t)(m0 - 512 + r) * ldc2 + n0] = (OutT)acc[i][j][r];
        }
      } else if constexpr (MODE == 2) {
#pragma unroll
        for (int r = 0; r < 4; r++) {
          _Float16 h = (_Float16)acc[i][j][r];
          C[(size_t)(m0 + r) * ldc + n0] = h;
          acc[i][j][r] = (float)h;  // rounded value feeds the stats
        }
      } else {
#pragma unroll
        for (int r = 0; r < 4; r++)
          C[(size_t)(m0 + r) * ldc + n0] = (OutT)acc[i][j][r];
      }
    }
  }

  // fused partial softmax stats: per column n, over this block's 128 m's.
  if constexpr (MODE == 2) {
    __shared__ float sred[128][2][2];  // [n_local][m-wave-group][max|sum]
    float pM[4], pS[4];
#pragma unroll
    for (int j = 0; j < 4; j++) {
      float mx = acc[0][j][0];
#pragma unroll
      for (int i = 0; i < 4; i++)
#pragma unroll
        for (int r = 0; r < 4; r++) mx = fmaxf(mx, acc[i][j][r]);
      mx = fmaxf(mx, __shfl_xor(mx, 16, 64));
      mx = fmaxf(mx, __shfl_xor(mx, 32, 64));
      float es = 0.f;
#pragma unroll
      for (int i = 0; i < 4; i++)
#pragma unroll
        for (int r = 0; r < 4; r++) es += __expf(acc[i][j][r] - mx);
      es += __shfl_xor(es, 16, 64);
      es += __shfl_xor(es, 32, 64);
      pM[j] = mx;
      pS[j] = es;
    }
    if (quad == 0) {
#pragma unroll
      for (int j = 0; j < 4; j++) {
        sred[wn + j * 16 + l16][wave & 1][0] = pM[j];
        sred[wn + j * 16 + l16][wave & 1][1] = pS[j];
      }
    }
    __syncthreads();
    if (t < 128) {
      float m0 = sred[t][0][0], s0 = sred[t][0][1];
      float m1 = sred[t][1][0], s1 = sred[t][1][1];
      float M = fmaxf(m0, m1);
      float S = s0 * __expf(m0 - M) + s1 * __expf(m1 - M);
      size_t o = ((size_t)blockIdx.z * 16 + blockIdx.y) * 2048 + n_blk + t;
      pm[o] = M;
      ps[o] = S;
    }
  }
}

// ---------------------------------------------------------------------------
// Column-stats stage 2: merge 16 partials -> shift[col] = max + ln(sum), so
// attn weight = exp(x - shift).  Grid (nb*2048/256).
// ---------------------------------------------------------------------------
__global__ __launch_bounds__(256) void colstats2(const float* __restrict__ pm,
                                                 const float* __restrict__ ps,
                                                 float* __restrict__ shift) {
  const int idx = blockIdx.x * 256 + threadIdx.x;  // b*2048 + col
  const int b = idx >> 11, col = idx & 2047;
  const float* pmb = pm + (size_t)b * 16 * 2048 + col;
  const float* psb = ps + (size_t)b * 16 * 2048 + col;
  float m = -3.0e38f;
#pragma unroll
  for (int i = 0; i < 16; i++) m = fmaxf(m, pmb[(size_t)i * 2048]);
  float s = 0.f;
#pragma unroll
  for (int i = 0; i < 16; i++)
    s += psb[(size_t)i * 2048] * __expf(pmb[(size_t)i * 2048] - m);
  shift[idx] = m + __logf(s);
}

// ---------------------------------------------------------------------------
// Stage-D fused: out[m][c] = sum_k exp(simH[m][k]-shift[k]) * V[c][k].
// simH fp16 [2048][2048] logits (per batch), V fp16 [512][2048],
// out fp32 [2048][512].  Block 256 = 4 waves, tile 128m x 128c, dbuf.
// A-staging via VGPR: load logits + shift, exp, ds_write (XOR-swizzled slot);
// B(v) via async global_load_lds.  XCD swizzle (cb==8): batch = lin&7 so one
// batch is co-resident per XCD; the 4 c-blocks of each m-tile are adjacent ->
// A-tiles fetched once into that XCD's L2.
// Grid: dim3(64*cb).
// ---------------------------------------------------------------------------
__global__ __launch_bounds__(256) void gemm_av(const _Float16* __restrict__ A,
                                               const _Float16* __restrict__ V,
                                               const float* __restrict__ shift,
                                               float* __restrict__ C,
                                               int cbatch) {
  int lin = blockIdx.x, z, idx;
  if (cbatch == 8) {
    z = lin & 7;
    idx = lin >> 3;
  } else {
    z = lin >> 6;
    idx = lin & 63;
  }
  const int n_blk = (idx & 3) * 128;   // c-dim
  const int m_blk = (idx >> 2) * 128;  // m-dim
  A += (size_t)z * 2048 * 2048;
  V += (size_t)z * 512 * 2048;
  shift += (size_t)z * 2048;
  C += (size_t)z * 2048 * 512;

  __shared__ _Float16 As[2][4096];
  __shared__ _Float16 Bs[2][4096];

  const int t = threadIdx.x;
  const int lane = t & 63, wave = t >> 6;
  const int quad = lane >> 4, l16 = lane & 15;
  const int wm = (wave & 1) * 64, wn = (wave >> 1) * 64;

  const int srow = 16 * wave + (lane >> 2);
  const int schunk = (lane & 3) ^ ((lane >> 3) & 3);  // XOR swizzle
  const _Float16* gA0 = A + (size_t)(m_blk + srow) * 2048 + schunk * 8;
  const _Float16* gA1 = gA0 + (size_t)64 * 2048;
  const _Float16* gB0 = V + (size_t)(n_blk + srow) * 2048 + schunk * 8;
  const _Float16* gB1 = gB0 + (size_t)64 * 2048;
  const float* gS = shift + schunk * 8;
  const int lofs = wave * 512 + lane * 8;
  const int rchunk = (quad ^ ((l16 >> 1) & 3)) * 8;

  f32x4 acc[4][4] = {};

  auto expw = [](half8 a, f32x4 s0, f32x4 s1) -> half8 {
    half8 o;
#pragma unroll
    for (int j = 0; j < 4; j++) {
      o[j] = (_Float16)__expf((float)a[j] - s0[j]);
      o[j + 4] = (_Float16)__expf((float)a[j + 4] - s1[j]);
    }
    return o;
  };

  // prologue: tile 0 into buf 0
  ASYNC_CP16(gB0, &Bs[0][lofs]);
  ASYNC_CP16(gB1, &Bs[0][lofs + 2048]);
  {
    half8 a0 = *(const half8*)gA0;
    half8 a1 = *(const half8*)gA1;
    f32x4 s0 = *(const f32x4*)gS;
    f32x4 s1 = *(const f32x4*)(gS + 4);
    *(half8*)&As[0][lofs] = expw(a0, s0, s1);
    *(half8*)&As[0][lofs + 2048] = expw(a1, s0, s1);
  }
  __syncthreads();

  int ib = 0;
  for (int k0 = 0; k0 < 2048; k0 += 32, ib ^= 1) {
    half8 a0, a1;
    f32x4 s0, s1;
    const bool more = (k0 + 32 < 2048);
    if (more) {  // issue next tile's loads first (B async, A+shift to regs)
      ASYNC_CP16(gB0 + k0 + 32, &Bs[ib ^ 1][lofs]);
      ASYNC_CP16(gB1 + k0 + 32, &Bs[ib ^ 1][lofs + 2048]);
      a0 = *(const half8*)(gA0 + k0 + 32);
      a1 = *(const half8*)(gA1 + k0 + 32);
      s0 = *(const f32x4*)(gS + k0 + 32);
      s1 = *(const f32x4*)(gS + k0 + 36);
    }
    half8 af[4], bf[4];
#pragma unroll
    for (int i = 0; i < 4; i++) {
      af[i] = *(const half8*)&As[ib][(wm + i * 16 + l16) * 32 + rchunk];
      bf[i] = *(const half8*)&Bs[ib][(wn + i * 16 + l16) * 32 + rchunk];
    }
#pragma unroll
    for (int i = 0; i < 4; i++)
#pragma unroll
      for (int j = 0; j < 4; j++)
        acc[i][j] =
            __builtin_amdgcn_mfma_f32_16x16x32_f16(af[i], bf[j], acc[i][j], 0, 0, 0);
    if (more) {  // exp + publish A for next tile
      *(half8*)&As[ib ^ 1][lofs] = expw(a0, s0, s1);
      *(half8*)&As[ib ^ 1][lofs + 2048] = expw(a1, s0, s1);
    }
    __syncthreads();
  }

  // epilogue: natural fp32 store C[m][c]
#pragma unroll
  for (int i = 0; i < 4; i++) {
    const int m0 = m_blk + wm + i * 16 + quad * 4;
#pragma unroll
    for (int j = 0; j < 4; j++) {
      const int n0 = n_blk + wn + j * 16 + l16;
#pragma unroll
      for (int r = 0; r < 4; r++) C[(size_t)(m0 + r) * 512 + n0] = acc[i][j][r];
    }
  }
}

// ---------------------------------------------------------------------------
extern "C" void kernel_launch(void* const* d_in, const int* in_sizes, int n_in,
                              void* d_out, int out_size, void* d_ws,
                              size_t ws_size, hipStream_t stream) {
  const float* x = (const float*)d_in[0];
  const float* Wq = (const float*)d_in[1];
  const float* Wk = (const float*)d_in[2];
  const float* Wv = (const float*)d_in[3];
  float* out = (float*)d_out;

  char* p = (char*)d_ws;
  auto alloc = [&](size_t bytes) -> char* {
    char* r = p;
    p += (bytes + 255) & ~(size_t)255;
    return r;
  };
  const size_t NB = 8, N = 2048, CIN = 512, CO = 512;
  _Float16* Wb = (_Float16*)alloc(1024 * 512 * sizeof(_Float16));
  _Float16* xT = (_Float16*)alloc(NB * N * CIN * sizeof(_Float16));
  _Float16* qkT = (_Float16*)alloc(NB * N * 512 * sizeof(_Float16));  // [n][q|k]
  _Float16* v = (_Float16*)alloc(NB * CO * N * sizeof(_Float16));     // [c][n]
  size_t base_used = (size_t)(p - (char*)d_ws);

  // per-batch bytes for the sim chain: fp16 logits + partials + shift + slack
  const size_t per_b = (size_t)N * N * 2 + 2 * 16 * N * 4 + N * 4 + 8192;
  int cb = 8;
  while (cb > 1 && base_used + (size_t)cb * per_b > ws_size) cb >>= 1;
  _Float16* simH = (_Float16*)alloc((size_t)cb * N * N * 2);
  float* pm = (float*)alloc((size_t)cb * 16 * N * 4);
  float* ps = (float*)alloc((size_t)cb * 16 * N * 4);
  float* shift = (float*)alloc((size_t)cb * N * 4);

  // 1) weight convert + x transpose-convert
  conv_w<<<dim3(1024 * 512 / 256), 256, 0, stream>>>(Wq, Wk, Wv, Wb);
  conv_xT<<<dim3(64, 16, 8), 256, 0, stream>>>(x, xT);

  // 2) merged projections (q,k,v in one pass over xT):
  //    rows<512 -> qkT[n][o] transposed; rows>=512 -> v[c][n] natural
  gemm_nt<_Float16, 3, 1><<<dim3(16, 8, 8), 256, 0, stream>>>(
      Wb, xT, qkT, v, 512, 512, 512, 512, 2048, 0, (long)(N * CIN),
      (long)(N * 512), nullptr, nullptr);

  // 3) per-chunk: simH[m][k] = fp16(qT . kT^T) natural, with fused softmax
  //    partials over m; merge stats -> shift; fused exp+AV GEMM -> out
  for (int b0 = 0; b0 < 8; b0 += cb) {
    const _Float16* qT = qkT + (size_t)b0 * N * 512;        // [m][c], lda 512
    const _Float16* kT = qkT + (size_t)b0 * N * 512 + 256;  // [k][c], ldb 512
    gemm_nt<_Float16, 2, 2><<<dim3(16, 16, cb), 256, 0, stream>>>(
        qT, kT, simH, nullptr, 256, 512, 512, 2048, 0, (long)(N * 512),
        (long)(N * 512), (long)(N * N), pm, ps);
    colstats2<<<dim3(cb * 8), 256, 0, stream>>>(pm, ps, shift);
    gemm_av<<<dim3(64 * cb), 256, 0, stream>>>(
        simH, v + (size_t)b0 * CO * N, shift, out + (size_t)b0 * N * CO, cb);
  }
}

// Round 9
// 211.079 us; speedup vs baseline: 2.3935x; 1.0681x over previous
//
#include <hip/hip_runtime.h>

typedef _Float16 half8 __attribute__((ext_vector_type(8)));
typedef _Float16 half4v __attribute__((ext_vector_type(4)));
typedef _Float16 half2v __attribute__((ext_vector_type(2)));
typedef float f32x4 __attribute__((ext_vector_type(4)));

// async 16B global->LDS copy (HW: LDS dest = wave-uniform base + lane*16)
#define ASYNC_CP16(gp, lp)                                       \
  __builtin_amdgcn_global_load_lds(                              \
      (const __attribute__((address_space(1))) void*)(gp),       \
      (__attribute__((address_space(3))) void*)(lp), 16, 0, 0)

static __device__ __forceinline__ half8 mulw(half8 a, half8 s) {
  half8 o;
#pragma unroll
  for (int j = 0; j < 8; j++) o[j] = a[j] * s[j];  // v_pk_mul_f16 x4
  return o;
}

// ---------------------------------------------------------------------------
// Convert Wq||Wk||Wv (fp32 [O,512] each) -> Wb fp16 [1024][512] (c-inner)
// ---------------------------------------------------------------------------
__global__ __launch_bounds__(256) void conv_w(const float* __restrict__ Wq,
                                              const float* __restrict__ Wk,
                                              const float* __restrict__ Wv,
                                              _Float16* __restrict__ Wb) {
  int idx = blockIdx.x * 256 + threadIdx.x;  // 0 .. 1024*512
  int row = idx >> 9;
  float v;
  if (row < 256)      v = Wq[idx];
  else if (row < 512) v = Wk[idx - 256 * 512];
  else                v = Wv[idx - 512 * 512];
  Wb[idx] = (_Float16)v;
}

// ---------------------------------------------------------------------------
// x fp32 [B][512][2048] -> xT fp16 [B][2048][512]   (LDS-tiled transpose)
// ---------------------------------------------------------------------------
__global__ __launch_bounds__(256) void conv_xT(const float* __restrict__ x,
                                               _Float16* __restrict__ xT) {
  __shared__ float T[32][33];
  const int b = blockIdx.z;
  const int n0 = blockIdx.x * 32, c0 = blockIdx.y * 32;
  const int t = threadIdx.x;
  const float* xb = x + (size_t)b * 512 * 2048;
  const int n2 = t & 15, cr = t >> 4;  // load: 16 float2-cols x 16 c-rows
#pragma unroll
  for (int r = 0; r < 2; r++) {
    int c = cr + r * 16;
    float2 v = *(const float2*)&xb[(size_t)(c0 + c) * 2048 + n0 + n2 * 2];
    T[c][n2 * 2] = v.x;
    T[c][n2 * 2 + 1] = v.y;
  }
  __syncthreads();
  _Float16* xtb = xT + (size_t)b * 2048 * 512;
  const int c2 = t & 15, nr = t >> 4;  // store: 16 half2-cols x 16 n-rows
#pragma unroll
  for (int r = 0; r < 2; r++) {
    int n = nr + r * 16;
    half2v h;
    h[0] = (_Float16)T[c2 * 2][n];
    h[1] = (_Float16)T[c2 * 2 + 1][n];
    *(half2v*)&xtb[(size_t)(n0 + n) * 512 + c0 + c2 * 2] = h;
  }
}

// ---------------------------------------------------------------------------
// NT-GEMM (proj + sim): C[m][n] = sum_k A[m][k]*B[n][k], fp16 in.
// Block 256 thr = 4 waves; block tile 128x128; wave tile 64x64 (4x4 MFMAs).
// BUFS-buffered async staging (global_load_lds w=16), prefetch dist BUFS-1,
// raw-asm barrier (vmcnt(4) mid-loop for BUFS=3; in-order vmcnt retire).
// XOR swizzle on the GLOBAL source side keeps frag ds_read_b128 conflict-free:
//   LDS slot (row r, 16B-chunk c') holds global chunk c' ^ ((r>>1)&3).
// MODE 1 (PROJ3): m_blk<512 -> transposed fp16 store into C (qkT); else
//   natural fp16 store into C2 (v) at row m-512.
// MODE 2 (SIM): store h = fp16(exp(logit - mx)) where mx is the PER-WAVE
//   column max over its 64 m's; emit partials pm=mx, ps=sum(rounded h) at
//   64-row granularity: pm/ps[b][32][2048].  (no cross-wave merge needed)
// ---------------------------------------------------------------------------
template <typename OutT, int BUFS, int MODE>
__global__ __launch_bounds__(256) void gemm_nt(
    const _Float16* __restrict__ A, const _Float16* __restrict__ B,
    OutT* __restrict__ C, OutT* __restrict__ C2, int K, int lda, int ldb,
    int ldc, int ldc2, long sA, long sB, long sC, float* __restrict__ pm,
    float* __restrict__ ps) {
  A += (size_t)blockIdx.z * sA;
  B += (size_t)blockIdx.z * sB;
  C += (size_t)blockIdx.z * sC;
  if constexpr (MODE == 1) C2 += (size_t)blockIdx.z * sC;
  const int m_blk = blockIdx.y * 128, n_blk = blockIdx.x * 128;

  __shared__ _Float16 As[BUFS][4096];  // [buf][128 rows][32 k halves]
  __shared__ _Float16 Bs[BUFS][4096];

  const int t = threadIdx.x;
  const int lane = t & 63, wave = t >> 6;
  const int quad = lane >> 4, l16 = lane & 15;
  const int wm = (wave & 1) * 64, wn = (wave >> 1) * 64;

  const int srow = 16 * wave + (lane >> 2);
  const int schunk = (lane & 3) ^ ((lane >> 3) & 3);  // XOR swizzle
  const _Float16* gA0 = A + (size_t)(m_blk + srow) * lda + schunk * 8;
  const _Float16* gA1 = gA0 + (size_t)64 * lda;
  const _Float16* gB0 = B + (size_t)(n_blk + srow) * ldb + schunk * 8;
  const _Float16* gB1 = gB0 + (size_t)64 * ldb;
  const int lofs = wave * 512 + lane * 8;  // halves within one buffer

  const int rchunk = (quad ^ ((l16 >> 1) & 3)) * 8;

  f32x4 acc[4][4] = {};

#pragma unroll
  for (int pb = 0; pb < BUFS - 1; pb++) {
    if (pb * 32 < K) {
      ASYNC_CP16(gA0 + pb * 32, &As[pb][lofs]);
      ASYNC_CP16(gA1 + pb * 32, &As[pb][lofs + 2048]);
      ASYNC_CP16(gB0 + pb * 32, &Bs[pb][lofs]);
      ASYNC_CP16(gB1 + pb * 32, &Bs[pb][lofs + 2048]);
    }
  }

  int ib = 0;
  for (int k0 = 0; k0 < K; k0 += 32) {
    if constexpr (BUFS == 3) {
      if (k0 + 32 < K)
        asm volatile("s_waitcnt vmcnt(4)\n\ts_barrier" ::: "memory");
      else
        asm volatile("s_waitcnt vmcnt(0)\n\ts_barrier" ::: "memory");
    } else {
      asm volatile("s_waitcnt vmcnt(0)\n\ts_barrier" ::: "memory");
    }
    if (k0 + (BUFS - 1) * 32 < K) {
      int nb = ib + BUFS - 1;
      if (nb >= BUFS) nb -= BUFS;
      const int ko = k0 + (BUFS - 1) * 32;
      ASYNC_CP16(gA0 + ko, &As[nb][lofs]);
      ASYNC_CP16(gA1 + ko, &As[nb][lofs + 2048]);
      ASYNC_CP16(gB0 + ko, &Bs[nb][lofs]);
      ASYNC_CP16(gB1 + ko, &Bs[nb][lofs + 2048]);
    }
    half8 af[4], bf[4];
#pragma unroll
    for (int i = 0; i < 4; i++) {
      af[i] = *(const half8*)&As[ib][(wm + i * 16 + l16) * 32 + rchunk];
      bf[i] = *(const half8*)&Bs[ib][(wn + i * 16 + l16) * 32 + rchunk];
    }
#pragma unroll
    for (int i = 0; i < 4; i++)
#pragma unroll
      for (int j = 0; j < 4; j++)
        acc[i][j] =
            __builtin_amdgcn_mfma_f32_16x16x32_f16(af[i], bf[j], acc[i][j], 0, 0, 0);
    ib++;
    if (ib == BUFS) ib = 0;
  }

  if constexpr (MODE == 2) {
    // per-wave-column softmax partials + exp-store (D row = quad*4+reg,
    // col = l16 in each 16x16 tile; wave column has 64 m's across i,quad,r)
#pragma unroll
    for (int j = 0; j < 4; j++) {
      const int n0 = n_blk + wn + j * 16 + l16;
      float mx = acc[0][j][0];
#pragma unroll
      for (int i = 0; i < 4; i++)
#pragma unroll
        for (int r = 0; r < 4; r++) mx = fmaxf(mx, acc[i][j][r]);
      mx = fmaxf(mx, __shfl_xor(mx, 16, 64));
      mx = fmaxf(mx, __shfl_xor(mx, 32, 64));
      float es = 0.f;
#pragma unroll
      for (int i = 0; i < 4; i++) {
        const int m0 = m_blk + wm + i * 16 + quad * 4;
#pragma unroll
        for (int r = 0; r < 4; r++) {
          _Float16 h = (_Float16)__expf(acc[i][j][r] - mx);
          C[(size_t)(m0 + r) * ldc + n0] = h;
          es += (float)h;
        }
      }
      es += __shfl_xor(es, 16, 64);
      es += __shfl_xor(es, 32, 64);
      if (quad == 0) {
        size_t o =
            ((size_t)blockIdx.z * 32 + blockIdx.y * 2 + (wave & 1)) * 2048 + n0;
        pm[o] = mx;
        ps[o] = es;
      }
    }
  } else {
#pragma unroll
    for (int i = 0; i < 4; i++) {
      const int m0 = m_blk + wm + i * 16 + quad * 4;
#pragma unroll
      for (int j = 0; j < 4; j++) {
        const int n0 = n_blk + wn + j * 16 + l16;
        if constexpr (MODE == 1) {
          if (m_blk < 512) {  // q|k rows: transposed store into qkT
            half4v h;
#pragma unroll
            for (int r = 0; r < 4; r++) h[r] = (_Float16)acc[i][j][r];
            *(half4v*)&C[(size_t)n0 * ldc + m0] = h;
          } else {  // v rows: natural store v[(m-512)][n]
#pragma unroll
            for (int r = 0; r < 4; r++)
              C2[(size_t)(m0 - 512 + r) * ldc2 + n0] = (OutT)acc[i][j][r];
          }
        } else {
#pragma unroll
          for (int r = 0; r < 4; r++)
            C[(size_t)(m0 + r) * ldc + n0] = (OutT)acc[i][j][r];
        }
      }
    }
  }
}

// ---------------------------------------------------------------------------
// Merge 32 per-64-row partials per column -> fp16 scale[b][32][2048]:
// scale[i][col] = exp(pm_i - M) / S,  S = sum_i ps_i * exp(pm_i - M).
// attn[m,k] = h[m,k] * scale[m>>6, k]; normalization exact by construction.
// Grid (nb*2048/256).
// ---------------------------------------------------------------------------
__global__ __launch_bounds__(256) void colstats2(const float* __restrict__ pm,
                                                 const float* __restrict__ ps,
                                                 _Float16* __restrict__ scl) {
  const int idx = blockIdx.x * 256 + threadIdx.x;  // b*2048 + col
  const int b = idx >> 11, col = idx & 2047;
  const float* pmb = pm + (size_t)b * 32 * 2048 + col;
  const float* psb = ps + (size_t)b * 32 * 2048 + col;
  float pv[32];
  float m = -3.0e38f;
#pragma unroll
  for (int i = 0; i < 32; i++) {
    pv[i] = pmb[(size_t)i * 2048];
    m = fmaxf(m, pv[i]);
  }
  float s = 0.f;
#pragma unroll
  for (int i = 0; i < 32; i++) {
    pv[i] = __expf(pv[i] - m);
    s += psb[(size_t)i * 2048] * pv[i];
  }
  const float inv = 1.0f / s;
  _Float16* so = scl + (size_t)b * 32 * 2048 + col;
#pragma unroll
  for (int i = 0; i < 32; i++) so[(size_t)i * 2048] = (_Float16)(pv[i] * inv);
}

// ---------------------------------------------------------------------------
// Stage-D: out[m][c] = sum_k (P[m][k]*scale[m>>6,k]) * V[c][k].
// P fp16 [2048][2048] (unnormalized exp), V fp16 [512][2048], scale fp16
// [32][2048] per batch, out fp32 [2048][512].
// Block 256 = 4 waves, tile 128m x 128c.  B: 3 LDS bufs, async dist 2.
// A: regs prefetch dist 2, staged via v_pk_mul_f16 + ds_write (XOR slot).
// Barrier: vmcnt(6) lgkmcnt(0) — the mul's auto-wait on A-regs (issued after
// the needed B tile; in-order vmcnt) already forces that B tile landed.
// XCD swizzle (cb==8): batch = lin&7 -> one batch per XCD, c-blocks adjacent.
// ---------------------------------------------------------------------------
__global__ __launch_bounds__(256) void gemm_av(const _Float16* __restrict__ P,
                                               const _Float16* __restrict__ V,
                                               const _Float16* __restrict__ scl,
                                               float* __restrict__ C,
                                               int cbatch) {
  int lin = blockIdx.x, z, idx;
  if (cbatch == 8) {
    z = lin & 7;
    idx = lin >> 3;
  } else {
    z = lin >> 6;
    idx = lin & 63;
  }
  const int n_blk = (idx & 3) * 128;   // c-dim
  const int m_blk = (idx >> 2) * 128;  // m-dim
  P += (size_t)z * 2048 * 2048;
  V += (size_t)z * 512 * 2048;
  scl += ((size_t)z * 32 + (m_blk >> 6)) * 2048;  // rows (m>>6) and (m>>6)+1
  C += (size_t)z * 2048 * 512;

  __shared__ _Float16 As[2][4096];
  __shared__ _Float16 Bs[3][4096];

  const int t = threadIdx.x;
  const int lane = t & 63, wave = t >> 6;
  const int quad = lane >> 4, l16 = lane & 15;
  const int wm = (wave & 1) * 64, wn = (wave >> 1) * 64;

  const int srow = 16 * wave + (lane >> 2);
  const int schunk = (lane & 3) ^ ((lane >> 3) & 3);  // XOR swizzle
  const _Float16* gA0 = P + (size_t)(m_blk + srow) * 2048 + schunk * 8;
  const _Float16* gA1 = gA0 + (size_t)64 * 2048;
  const _Float16* gB0 = V + (size_t)(n_blk + srow) * 2048 + schunk * 8;
  const _Float16* gB1 = gB0 + (size_t)64 * 2048;
  const _Float16* gS0 = scl + schunk * 8;
  const _Float16* gS1 = gS0 + 2048;
  const int lofs = wave * 512 + lane * 8;
  const int rchunk = (quad ^ ((l16 >> 1) & 3)) * 8;

  f32x4 acc[4][4] = {};

  // prologue: B tiles 0,1 async; A tile 0 staged; A tile 1 in regs
  ASYNC_CP16(gB0, &Bs[0][lofs]);
  ASYNC_CP16(gB1, &Bs[0][lofs + 2048]);
  ASYNC_CP16(gB0 + 32, &Bs[1][lofs]);
  ASYNC_CP16(gB1 + 32, &Bs[1][lofs + 2048]);
  {
    half8 a0 = *(const half8*)gA0;
    half8 a1 = *(const half8*)gA1;
    half8 s0 = *(const half8*)gS0;
    half8 s1 = *(const half8*)gS1;
    *(half8*)&As[0][lofs] = mulw(a0, s0);
    *(half8*)&As[0][lofs + 2048] = mulw(a1, s1);
  }
  half8 an0 = *(const half8*)(gA0 + 32);
  half8 an1 = *(const half8*)(gA1 + 32);
  half8 sn0 = *(const half8*)(gS0 + 32);
  half8 sn1 = *(const half8*)(gS1 + 32);
  __syncthreads();

  int ibA = 0, ibB = 0;
  for (int k0 = 0; k0 < 2048; k0 += 32) {
    const bool m1 = (k0 + 32 < 2048), m2 = (k0 + 64 < 2048);
    if (m2) {  // B tile k+2 (issued FIRST: the A-reg waits then imply B done)
      int nb = ibB + 2;
      if (nb >= 3) nb -= 3;
      ASYNC_CP16(gB0 + k0 + 64, &Bs[nb][lofs]);
      ASYNC_CP16(gB1 + k0 + 64, &Bs[nb][lofs + 2048]);
    }
    half8 a20, a21, s20, s21;
    if (m2) {  // A/scale tile k+2 into regs
      a20 = *(const half8*)(gA0 + k0 + 64);
      a21 = *(const half8*)(gA1 + k0 + 64);
      s20 = *(const half8*)(gS0 + k0 + 64);
      s21 = *(const half8*)(gS1 + k0 + 64);
    }
    half8 af[4], bf[4];
#pragma unroll
    for (int i = 0; i < 4; i++) {
      af[i] = *(const half8*)&As[ibA][(wm + i * 16 + l16) * 32 + rchunk];
      bf[i] = *(const half8*)&Bs[ibB][(wn + i * 16 + l16) * 32 + rchunk];
    }
#pragma unroll
    for (int i = 0; i < 4; i++)
#pragma unroll
      for (int j = 0; j < 4; j++)
        acc[i][j] =
            __builtin_amdgcn_mfma_f32_16x16x32_f16(af[i], bf[j], acc[i][j], 0, 0, 0);
    if (m1) {  // stage A tile k+1 (regs loaded last iter)
      *(half8*)&As[ibA ^ 1][lofs] = mulw(an0, sn0);
      *(half8*)&As[ibA ^ 1][lofs + 2048] = mulw(an1, sn1);
      if (m2) {
        an0 = a20;
        an1 = a21;
        sn0 = s20;
        sn1 = s21;
      }
      asm volatile("s_waitcnt vmcnt(6) lgkmcnt(0)\n\ts_barrier" ::: "memory");
    }
    ibA ^= 1;
    ibB++;
    if (ibB == 3) ibB = 0;
  }

  // epilogue: natural fp32 store C[m][c]
#pragma unroll
  for (int i = 0; i < 4; i++) {
    const int m0 = m_blk + wm + i * 16 + quad * 4;
#pragma unroll
    for (int j = 0; j < 4; j++) {
      const int n0 = n_blk + wn + j * 16 + l16;
#pragma unroll
      for (int r = 0; r < 4; r++) C[(size_t)(m0 + r) * 512 + n0] = acc[i][j][r];
    }
  }
}

// ---------------------------------------------------------------------------
extern "C" void kernel_launch(void* const* d_in, const int* in_sizes, int n_in,
                              void* d_out, int out_size, void* d_ws,
                              size_t ws_size, hipStream_t stream) {
  const float* x = (const float*)d_in[0];
  const float* Wq = (const float*)d_in[1];
  const float* Wk = (const float*)d_in[2];
  const float* Wv = (const float*)d_in[3];
  float* out = (float*)d_out;

  char* p = (char*)d_ws;
  auto alloc = [&](size_t bytes) -> char* {
    char* r = p;
    p += (bytes + 255) & ~(size_t)255;
    return r;
  };
  const size_t NB = 8, N = 2048, CIN = 512, CO = 512;
  _Float16* Wb = (_Float16*)alloc(1024 * 512 * sizeof(_Float16));
  _Float16* xT = (_Float16*)alloc(NB * N * CIN * sizeof(_Float16));
  _Float16* qkT = (_Float16*)alloc(NB * N * 512 * sizeof(_Float16));  // [n][q|k]
  _Float16* v = (_Float16*)alloc(NB * CO * N * sizeof(_Float16));     // [c][n]
  size_t base_used = (size_t)(p - (char*)d_ws);

  // per-batch bytes for the sim chain: fp16 P + partials + scale + slack
  const size_t per_b =
      (size_t)N * N * 2 + 2 * 32 * N * 4 + 32 * N * 2 + 8192;
  int cb = 8;
  while (cb > 1 && base_used + (size_t)cb * per_b > ws_size) cb >>= 1;
  _Float16* simH = (_Float16*)alloc((size_t)cb * N * N * 2);
  float* pm = (float*)alloc((size_t)cb * 32 * N * 4);
  float* ps = (float*)alloc((size_t)cb * 32 * N * 4);
  _Float16* scl = (_Float16*)alloc((size_t)cb * 32 * N * 2);

  // 1) weight convert + x transpose-convert
  conv_w<<<dim3(1024 * 512 / 256), 256, 0, stream>>>(Wq, Wk, Wv, Wb);
  conv_xT<<<dim3(64, 16, 8), 256, 0, stream>>>(x, xT);

  // 2) merged projections (q,k,v in one pass over xT):
  //    rows<512 -> qkT[n][o] transposed; rows>=512 -> v[c][n] natural
  gemm_nt<_Float16, 3, 1><<<dim3(16, 8, 8), 256, 0, stream>>>(
      Wb, xT, qkT, v, 512, 512, 512, 512, 2048, 0, (long)(N * CIN),
      (long)(N * 512), nullptr, nullptr);

  // 3) per-chunk: simH = fp16(exp(qT.kT^T - mx_wave)) + partials; merge ->
  //    fp16 scale; stage-D GEMM applies scale during A-staging -> out
  for (int b0 = 0; b0 < 8; b0 += cb) {
    const _Float16* qT = qkT + (size_t)b0 * N * 512;        // [m][c], lda 512
    const _Float16* kT = qkT + (size_t)b0 * N * 512 + 256;  // [k][c], ldb 512
    gemm_nt<_Float16, 2, 2><<<dim3(16, 16, cb), 256, 0, stream>>>(
        qT, kT, simH, nullptr, 256, 512, 512, 2048, 0, (long)(N * 512),
        (long)(N * 512), (long)(N * N), pm, ps);
    colstats2<<<dim3(cb * 8), 256, 0, stream>>>(pm, ps, scl);
    gemm_av<<<dim3(64 * cb), 256, 0, stream>>>(
        simH, v + (size_t)b0 * CO * N, scl, out + (size_t)b0 * N * CO, cb);
  }
}